// Round 6
// baseline (2444.057 us; speedup 1.0000x reference)
//
#include <hip/hip_runtime.h>
#include <math.h>

#define NPB 128        // nodes per bucket
#define CSTR 16        // counter padding stride (ints) -> one 64B line per counter
#define STAGE_CAP 3072 // LDS edge-stage capacity (mean ~2048, sigma ~45 -> safe)

// ---------------- bucket counting sort of edges ----------------

__global__ __launch_bounds__(256) void hist_bucket_kernel(
    const int* __restrict__ d1, const int* __restrict__ d2,
    int* __restrict__ bcnt, int E, int nbase2) {
  int e = blockIdx.x * 256 + threadIdx.x;
  if (e >= E) return;
  int dg = blockIdx.y ? (nbase2 + d2[e]) : d1[e];
  atomicAdd(&bcnt[(dg >> 7) * CSTR], 1);
}

__global__ __launch_bounds__(1024) void bucket_scan_kernel(
    const int* __restrict__ bcnt, int* __restrict__ boff,
    int* __restrict__ bcur, int nbuk, int total) {
  __shared__ int sd[1024];
  int tid = threadIdx.x;
  int v = (tid < nbuk) ? bcnt[tid * CSTR] : 0;
  sd[tid] = v;
  __syncthreads();
  for (int off = 1; off < 1024; off <<= 1) {
    int t = (tid >= off) ? sd[tid - off] : 0;
    __syncthreads();
    sd[tid] += t;
    __syncthreads();
  }
  if (tid < nbuk) {
    int excl = sd[tid] - v;
    boff[tid] = excl;
    bcur[tid * CSTR] = excl;
  }
  if (tid == 0) boff[nbuk] = total;
}

// Append (src | d_local<<17) into the dst's bucket region: dense writes per bucket.
__global__ __launch_bounds__(256) void scatter_kernel(
    const int* __restrict__ s1, const int* __restrict__ d1,
    const int* __restrict__ s2, const int* __restrict__ d2,
    int* __restrict__ bcur, int* __restrict__ pairs, int E, int nbase2) {
  int e = blockIdx.x * 256 + threadIdx.x;
  if (e >= E) return;
  int s, dg;
  if (blockIdx.y) { s = s2[e]; dg = nbase2 + d2[e]; }
  else           { s = s1[e]; dg = d1[e]; }
  int b = dg >> 7;
  int pos = atomicAdd(&bcur[b * CSTR], 1);
  pairs[pos] = s | ((dg & (NPB - 1)) << 17);
}

// ---------------- GEMM: Y[nrows,COUT] = X[nrows,128] @ W[128,COUT] + bias ----------------

template <int COUT>
__global__ __launch_bounds__(256, 2) void gemm_kernel(const float* __restrict__ X,
                                                      const float* __restrict__ W,
                                                      const float* __restrict__ bias,
                                                      float* __restrict__ Y, int nrows) {
  constexpr int CG = COUT / 4;
  constexpr int RG = 256 / CG;
  constexpr int BM = 64;
  constexpr int RPT = BM / RG;
  __shared__ float xs[BM][132];
  int tid = threadIdx.x;
  int block_row = blockIdx.x * BM;
  for (int i = tid; i < BM * 32; i += 256) {
    int r = i >> 5, c4 = i & 31;
    int gr = block_row + r;
    float4 v = make_float4(0.f, 0.f, 0.f, 0.f);
    if (gr < nrows) v = reinterpret_cast<const float4*>(X + (size_t)gr * 128)[c4];
    *reinterpret_cast<float4*>(&xs[r][c4 * 4]) = v;
  }
  __syncthreads();
  int c0 = (tid % CG) * 4;
  int r0 = (tid / CG) * RPT;
  float acc[RPT][4] = {};
  #pragma unroll 2
  for (int k = 0; k < 128; k += 4) {
    float4 w0 = *reinterpret_cast<const float4*>(&W[(k + 0) * COUT + c0]);
    float4 w1 = *reinterpret_cast<const float4*>(&W[(k + 1) * COUT + c0]);
    float4 w2 = *reinterpret_cast<const float4*>(&W[(k + 2) * COUT + c0]);
    float4 w3 = *reinterpret_cast<const float4*>(&W[(k + 3) * COUT + c0]);
    #pragma unroll
    for (int i = 0; i < RPT; ++i) {
      float4 x = *reinterpret_cast<const float4*>(&xs[r0 + i][k]);
      acc[i][0] = fmaf(x.x, w0.x, acc[i][0]);
      acc[i][1] = fmaf(x.x, w0.y, acc[i][1]);
      acc[i][2] = fmaf(x.x, w0.z, acc[i][2]);
      acc[i][3] = fmaf(x.x, w0.w, acc[i][3]);
      acc[i][0] = fmaf(x.y, w1.x, acc[i][0]);
      acc[i][1] = fmaf(x.y, w1.y, acc[i][1]);
      acc[i][2] = fmaf(x.y, w1.z, acc[i][2]);
      acc[i][3] = fmaf(x.y, w1.w, acc[i][3]);
      acc[i][0] = fmaf(x.z, w2.x, acc[i][0]);
      acc[i][1] = fmaf(x.z, w2.y, acc[i][1]);
      acc[i][2] = fmaf(x.z, w2.z, acc[i][2]);
      acc[i][3] = fmaf(x.z, w2.w, acc[i][3]);
      acc[i][0] = fmaf(x.w, w3.x, acc[i][0]);
      acc[i][1] = fmaf(x.w, w3.y, acc[i][1]);
      acc[i][2] = fmaf(x.w, w3.z, acc[i][2]);
      acc[i][3] = fmaf(x.w, w3.w, acc[i][3]);
    }
  }
  float4 bv = *reinterpret_cast<const float4*>(&bias[c0]);
  #pragma unroll
  for (int i = 0; i < RPT; ++i) {
    int gr = block_row + r0 + i;
    if (gr < nrows) {
      float4 o;
      o.x = acc[i][0] + bv.x; o.y = acc[i][1] + bv.y;
      o.z = acc[i][2] + bv.z; o.w = acc[i][3] + bv.w;
      *reinterpret_cast<float4*>(&Y[(size_t)gr * COUT + c0]) = o;
    }
  }
}

// ---------------- Bucketed aggregate + BN + relu ----------------
// One WG per 128-node bucket; 128xC fp32 accumulator in LDS; waves stream the
// bucket's (src|d_local) edges; lane c covers cols c and c+64 -> conflict-free ds_add.

template <int C>
__global__ __launch_bounds__(1024) void agg_bucket_kernel(
    const float* __restrict__ h, const int* __restrict__ pairs,
    const int* __restrict__ boff,
    const float* __restrict__ gamma, const float* __restrict__ beta,
    float* __restrict__ out, int bkt0, int n) {
  __shared__ float acc[NPB * C];
  __shared__ int stage[STAGE_CAP];
  int tid = threadIdx.x;
  int bkt = bkt0 + blockIdx.x;
  int pbase = boff[bkt], pcnt = boff[bkt + 1] - pbase;
  for (int i = tid; i < NPB * C; i += 1024) acc[i] = 0.f;
  int scnt = pcnt < STAGE_CAP ? pcnt : STAGE_CAP;
  for (int i = tid; i < scnt; i += 1024) stage[i] = pairs[pbase + i];
  __syncthreads();
  int lane = tid & 63, wv = tid >> 6;  // 16 waves
  int nch = scnt >> 2;
  for (int ch = wv; ch < nch; ch += 16) {
    int j = ch * 4;
    float v0[4], v1[4]; int dl[4];
    #pragma unroll
    for (int u = 0; u < 4; ++u) {
      int pk = stage[j + u];
      int s = pk & 0x1FFFF; dl[u] = pk >> 17;
      v0[u] = h[(size_t)s * C + lane];
      if (C == 128) v1[u] = h[(size_t)s * C + 64 + lane];
    }
    #pragma unroll
    for (int u = 0; u < 4; ++u) {
      atomicAdd(&acc[dl[u] * C + lane], v0[u]);
      if (C == 128) atomicAdd(&acc[dl[u] * C + 64 + lane], v1[u]);
    }
  }
  if (wv == 0) {  // stage tail (<=3 edges)
    for (int j = nch * 4; j < scnt; ++j) {
      int pk = stage[j]; int s = pk & 0x1FFFF; int d = pk >> 17;
      atomicAdd(&acc[d * C + lane], h[(size_t)s * C + lane]);
      if (C == 128) atomicAdd(&acc[d * C + 64 + lane], h[(size_t)s * C + 64 + lane]);
    }
  }
  for (int j = STAGE_CAP + wv; j < pcnt; j += 16) {  // overflow (statistically never)
    int pk = pairs[pbase + j]; int s = pk & 0x1FFFF; int d = pk >> 17;
    atomicAdd(&acc[d * C + lane], h[(size_t)s * C + lane]);
    if (C == 128) atomicAdd(&acc[d * C + 64 + lane], h[(size_t)s * C + 64 + lane]);
  }
  __syncthreads();
  const float inv = 1.0f / sqrtf(1.0f + 1.0e-3f);
  float g0 = gamma[lane] * inv, b0 = beta[lane];
  float g1 = 0.f, b1 = 0.f;
  if (C == 128) { g1 = gamma[64 + lane] * inv; b1 = beta[64 + lane]; }
  int row0 = blockIdx.x * NPB;
  for (int r = wv; r < NPB; r += 16) {
    int row = row0 + r;
    if (row < n) {
      out[(size_t)row * C + lane] = fmaxf(fmaf(acc[r * C + lane], g0, b0), 0.f);
      if (C == 128)
        out[(size_t)row * C + 64 + lane] =
            fmaxf(fmaf(acc[r * C + 64 + lane], g1, b1), 0.f);
    }
  }
}

// ---------------- Segment mean pool (seg sorted): p[64,64] ----------------

__global__ __launch_bounds__(1024) void pool_kernel(const float* __restrict__ h,
                                                    const int* __restrict__ seg,
                                                    float* __restrict__ p, int n) {
  int g = blockIdx.x;
  int lo, hi;
  { int l = 0, r = n; while (l < r) { int m = (l + r) >> 1; if (seg[m] < g) l = m + 1; else r = m; } lo = l; }
  { int l = 0, r = n; while (l < r) { int m = (l + r) >> 1; if (seg[m] < g + 1) l = m + 1; else r = m; } hi = l; }
  int c = threadIdx.x & 63;
  int sub = threadIdx.x >> 6;
  float acc = 0.f;
  for (int i = lo + sub; i < hi; i += 16) acc += h[(size_t)i * 64 + c];
  __shared__ float red[16][64];
  red[sub][c] = acc;
  __syncthreads();
  if (sub == 0) {
    float s = 0.f;
    #pragma unroll
    for (int k = 0; k < 16; ++k) s += red[k][c];
    float cnt = (float)(hi - lo);
    p[g * 64 + c] = s / fmaxf(cnt, 1.0f);
  }
}

// ---------------- Head ----------------

__global__ __launch_bounds__(512) void head_kernel(const float* __restrict__ p,
                                                   const float* __restrict__ Wd,
                                                   const float* __restrict__ bd,
                                                   const float* __restrict__ Wo,
                                                   const float* __restrict__ bo,
                                                   float* __restrict__ out) {
  __shared__ float cur[64][128];
  __shared__ float nxt[64][128];
  int tid = threadIdx.x;
  const float* p1 = p;
  const float* p2 = p + 64 * 64;
  for (int i = tid; i < 64 * 128; i += 512) {
    int r = i >> 7, c = i & 127;
    cur[r][c] = (c < 64) ? p1[r * 64 + c] : p2[r * 64 + (c - 64)];
  }
  __syncthreads();
  int c0 = (tid & 31) * 4;
  int r0 = (tid >> 5) * 4;
  for (int layer = 0; layer < 2; ++layer) {
    float acc[4][4] = {};
    #pragma unroll 4
    for (int k = 0; k < 128; ++k) {
      float4 w = *reinterpret_cast<const float4*>(&Wd[k * 128 + c0]);
      #pragma unroll
      for (int i = 0; i < 4; ++i) {
        float x = cur[r0 + i][k];
        acc[i][0] = fmaf(x, w.x, acc[i][0]);
        acc[i][1] = fmaf(x, w.y, acc[i][1]);
        acc[i][2] = fmaf(x, w.z, acc[i][2]);
        acc[i][3] = fmaf(x, w.w, acc[i][3]);
      }
    }
    float4 bv = *reinterpret_cast<const float4*>(&bd[c0]);
    __syncthreads();
    #pragma unroll
    for (int i = 0; i < 4; ++i) {
      float4 o;
      o.x = fmaxf(acc[i][0] + bv.x, 0.f);
      o.y = fmaxf(acc[i][1] + bv.y, 0.f);
      o.z = fmaxf(acc[i][2] + bv.z, 0.f);
      o.w = fmaxf(acc[i][3] + bv.w, 0.f);
      *reinterpret_cast<float4*>(&nxt[r0 + i][c0]) = o;
    }
    __syncthreads();
    for (int i = tid; i < 64 * 128; i += 512) (&cur[0][0])[i] = (&nxt[0][0])[i];
    __syncthreads();
  }
  int wv = tid >> 6, lane = tid & 63;
  for (int r = wv; r < 64; r += 8) {
    float v = cur[r][lane] * Wo[lane] + cur[r][64 + lane] * Wo[64 + lane];
    #pragma unroll
    for (int off = 32; off; off >>= 1) v += __shfl_down(v, off);
    if (lane == 0) out[r] = 1.0f / (1.0f + expf(-(v + bo[0])));
  }
}

// ---------------- launch ----------------

extern "C" void kernel_launch(void* const* d_in, const int* in_sizes, int n_in,
                              void* d_out, int out_size, void* d_ws, size_t ws_size,
                              hipStream_t stream) {
  const float* x1  = (const float*)d_in[0];
  const float* x2  = (const float*)d_in[1];
  const int* e1    = (const int*)d_in[2];
  const int* e2    = (const int*)d_in[3];
  const int* seg1  = (const int*)d_in[4];
  const int* seg2  = (const int*)d_in[5];
  const float* W1a = (const float*)d_in[6];  const float* b1a = (const float*)d_in[7];
  const float* g1a = (const float*)d_in[8];  const float* be1a = (const float*)d_in[9];
  const float* W1b = (const float*)d_in[10]; const float* b1b = (const float*)d_in[11];
  const float* g1b = (const float*)d_in[12]; const float* be1b = (const float*)d_in[13];
  const float* W2a = (const float*)d_in[14]; const float* b2a = (const float*)d_in[15];
  const float* g2a = (const float*)d_in[16]; const float* be2a = (const float*)d_in[17];
  const float* W2b = (const float*)d_in[18]; const float* b2b = (const float*)d_in[19];
  const float* g2b = (const float*)d_in[20]; const float* be2b = (const float*)d_in[21];
  const float* Wd  = (const float*)d_in[22]; const float* bd  = (const float*)d_in[23];
  const float* Wo  = (const float*)d_in[24]; const float* bo  = (const float*)d_in[25];
  float* out = (float*)d_out;

  const int N = in_sizes[0] / 128;
  const int E = in_sizes[2] / 2;
  const int nb_pad = (N + NPB - 1) & ~(NPB - 1);          // branch-2 node base
  const int nbuk1  = nb_pad >> 7;                          // branch-1 bucket count
  const int nbuk   = (nb_pad + N + NPB - 1) >> 7;          // total buckets

  char* ws = (char*)d_ws;
  size_t off = 0;
  auto alloc = [&](size_t bytes) -> void* {
    void* ptr = ws + off;
    off += (bytes + 255) & ~(size_t)255;
    return ptr;
  };
  float* h    = (float*)alloc((size_t)N * 128 * sizeof(float));
  float* aggb = (float*)alloc((size_t)N * 128 * sizeof(float));
  int* pairs  = (int*)alloc((size_t)(2 * E) * sizeof(int));
  int* bcnt   = (int*)alloc((size_t)(2 * nbuk * CSTR) * sizeof(int));
  int* bcur   = bcnt + nbuk * CSTR;
  int* boff   = (int*)alloc((size_t)(nbuk + 1) * sizeof(int));
  float* pbuf = (float*)alloc(2 * 64 * 64 * sizeof(float));
  (void)ws_size; (void)n_in; (void)out_size;

  // ---- bucket counting sort of both branches' edges ----
  hipMemsetAsync(bcnt, 0, (size_t)(2 * nbuk * CSTR) * sizeof(int), stream);
  {
    dim3 g((E + 255) / 256, 2);
    hist_bucket_kernel<<<g, 256, 0, stream>>>(e1 + E, e2 + E, bcnt, E, nb_pad);
    bucket_scan_kernel<<<1, 1024, 0, stream>>>(bcnt, boff, bcur, nbuk, 2 * E);
    scatter_kernel<<<g, 256, 0, stream>>>(e1, e1 + E, e2, e2 + E, bcur, pairs, E, nb_pad);
  }

  struct Branch {
    const float *x; const int *seg;
    const float *Wa, *ba, *ga, *bea, *Wb, *bb, *gb, *beb;
    int bkt0, nbk;
  };
  Branch brs[2] = {
    {x1, seg1, W1a, b1a, g1a, be1a, W1b, b1b, g1b, be1b, 0, nbuk1},
    {x2, seg2, W2a, b2a, g2a, be2a, W2b, b2b, g2b, be2b, nbuk1, nbuk - nbuk1},
  };

  for (int b = 0; b < 2; ++b) {
    gemm_kernel<128><<<(N + 63) / 64, 256, 0, stream>>>(brs[b].x, brs[b].Wa, brs[b].ba, h, N);
    agg_bucket_kernel<128><<<brs[b].nbk, 1024, 0, stream>>>(h, pairs, boff, brs[b].ga, brs[b].bea, aggb, brs[b].bkt0, N);
    gemm_kernel<64><<<(N + 63) / 64, 256, 0, stream>>>(aggb, brs[b].Wb, brs[b].bb, h, N);
    agg_bucket_kernel<64><<<brs[b].nbk, 1024, 0, stream>>>(h, pairs, boff, brs[b].gb, brs[b].beb, aggb, brs[b].bkt0, N);
    pool_kernel<<<64, 1024, 0, stream>>>(aggb, brs[b].seg, pbuf + b * 64 * 64, N);
  }
  head_kernel<<<1, 512, 0, stream>>>(pbuf, Wd, bd, Wo, bo, out);
}

// Round 7
// 545.153 us; speedup vs baseline: 4.4832x; 4.4832x over previous
//
#include <hip/hip_runtime.h>
#include <math.h>

// ---------------- CSR build (both branches fused; cursor holds absolute positions) ----------------

__global__ __launch_bounds__(256) void hist2_kernel(const int* __restrict__ d1,
                                                    const int* __restrict__ d2,
                                                    int* __restrict__ counts, int E, int N) {
  int e = blockIdx.x * 256 + threadIdx.x;
  const int* dst = blockIdx.y ? d2 : d1;
  int nb = blockIdx.y * N;
  if (e < E) atomicAdd(&counts[nb + dst[e]], 1);
}

// Per-wave shuffle scan + one atomicAdd per wave over 2N nodes.
// Writes exclusive base into BOTH offs (for agg) and cursor (for fill).
__global__ __launch_bounds__(256) void alloc_kernel(const int* __restrict__ counts,
                                                    int* __restrict__ offs,
                                                    int* __restrict__ cursor,
                                                    int* __restrict__ gcur, int n2) {
  int i = blockIdx.x * 256 + threadIdx.x;
  int lane = threadIdx.x & 63;
  int cnt = (i < n2) ? counts[i] : 0;
  int v = cnt;
  #pragma unroll
  for (int off = 1; off < 64; off <<= 1) {
    int t = __shfl_up(v, off);
    if (lane >= off) v += t;
  }
  int base = 0;
  if (lane == 63) base = atomicAdd(gcur, v);
  base = __shfl(base, 63);
  if (i < n2) {
    int excl = base + v - cnt;
    offs[i] = excl;
    cursor[i] = excl;
  }
}

// cursor[d] already holds the absolute base -> atomicAdd returns absolute slot.
__global__ __launch_bounds__(256) void fill2_kernel(const int* __restrict__ s1,
                                                    const int* __restrict__ d1,
                                                    const int* __restrict__ s2,
                                                    const int* __restrict__ d2,
                                                    int* __restrict__ cursor,
                                                    int* __restrict__ csr, int E, int N) {
  int e = blockIdx.x * 256 + threadIdx.x;
  const int* src = blockIdx.y ? s2 : s1;
  const int* dst = blockIdx.y ? d2 : d1;
  int nb = blockIdx.y * N;
  if (e < E) {
    int pos = atomicAdd(&cursor[nb + dst[e]], 1);
    csr[pos] = src[e];
  }
}

// ---------------- GEMM: Y[nrows,COUT] = X[nrows,128] @ W[128,COUT] + bias ----------------

template <int COUT>
__global__ __launch_bounds__(256, 2) void gemm_kernel(const float* __restrict__ X,
                                                      const float* __restrict__ W,
                                                      const float* __restrict__ bias,
                                                      float* __restrict__ Y, int nrows) {
  constexpr int CG = COUT / 4;
  constexpr int RG = 256 / CG;
  constexpr int BM = 64;
  constexpr int RPT = BM / RG;
  __shared__ float xs[BM][132];
  int tid = threadIdx.x;
  int block_row = blockIdx.x * BM;
  for (int i = tid; i < BM * 32; i += 256) {
    int r = i >> 5, c4 = i & 31;
    int gr = block_row + r;
    float4 v = make_float4(0.f, 0.f, 0.f, 0.f);
    if (gr < nrows) v = reinterpret_cast<const float4*>(X + (size_t)gr * 128)[c4];
    *reinterpret_cast<float4*>(&xs[r][c4 * 4]) = v;
  }
  __syncthreads();
  int c0 = (tid % CG) * 4;
  int r0 = (tid / CG) * RPT;
  float acc[RPT][4] = {};
  #pragma unroll 2
  for (int k = 0; k < 128; k += 4) {
    float4 w0 = *reinterpret_cast<const float4*>(&W[(k + 0) * COUT + c0]);
    float4 w1 = *reinterpret_cast<const float4*>(&W[(k + 1) * COUT + c0]);
    float4 w2 = *reinterpret_cast<const float4*>(&W[(k + 2) * COUT + c0]);
    float4 w3 = *reinterpret_cast<const float4*>(&W[(k + 3) * COUT + c0]);
    #pragma unroll
    for (int i = 0; i < RPT; ++i) {
      float4 x = *reinterpret_cast<const float4*>(&xs[r0 + i][k]);
      acc[i][0] = fmaf(x.x, w0.x, acc[i][0]);
      acc[i][1] = fmaf(x.x, w0.y, acc[i][1]);
      acc[i][2] = fmaf(x.x, w0.z, acc[i][2]);
      acc[i][3] = fmaf(x.x, w0.w, acc[i][3]);
      acc[i][0] = fmaf(x.y, w1.x, acc[i][0]);
      acc[i][1] = fmaf(x.y, w1.y, acc[i][1]);
      acc[i][2] = fmaf(x.y, w1.z, acc[i][2]);
      acc[i][3] = fmaf(x.y, w1.w, acc[i][3]);
      acc[i][0] = fmaf(x.z, w2.x, acc[i][0]);
      acc[i][1] = fmaf(x.z, w2.y, acc[i][1]);
      acc[i][2] = fmaf(x.z, w2.z, acc[i][2]);
      acc[i][3] = fmaf(x.z, w2.w, acc[i][3]);
      acc[i][0] = fmaf(x.w, w3.x, acc[i][0]);
      acc[i][1] = fmaf(x.w, w3.y, acc[i][1]);
      acc[i][2] = fmaf(x.w, w3.z, acc[i][2]);
      acc[i][3] = fmaf(x.w, w3.w, acc[i][3]);
    }
  }
  float4 bv = *reinterpret_cast<const float4*>(&bias[c0]);
  #pragma unroll
  for (int i = 0; i < RPT; ++i) {
    int gr = block_row + r0 + i;
    if (gr < nrows) {
      float4 o;
      o.x = acc[i][0] + bv.x; o.y = acc[i][1] + bv.y;
      o.z = acc[i][2] + bv.z; o.w = acc[i][3] + bv.w;
      *reinterpret_cast<float4*>(&Y[(size_t)gr * COUT + c0]) = o;
    }
  }
}

// ---------------- Aggregate (CSR gather-sum) + BN(inference) + relu ----------------
// Wave per node, half-wave split: one wide load covers a FULL row (C=128: 32 lanes x
// float4; C=64: 32 lanes x float2). Lanes 0-31 take even edges, 32-63 odd edges ->
// 2 edges per load instruction, 16 edges in flight per unroll window. Halves are
// combined with shfl_xor(,32) at the end.

template <int C>
__global__ __launch_bounds__(256) void agg_kernel(const float* __restrict__ h,
                                                  const int* __restrict__ offs,
                                                  const int* __restrict__ counts,
                                                  const int* __restrict__ csr_src,
                                                  const float* __restrict__ gamma,
                                                  const float* __restrict__ beta,
                                                  float* __restrict__ out, int n) {
  int node = blockIdx.x * 4 + (threadIdx.x >> 6);
  if (node >= n) return;
  node = __builtin_amdgcn_readfirstlane(node);
  int lane = threadIdx.x & 63;
  int half = lane >> 5;
  int l5 = lane & 31;
  int beg = offs[node], cnt = counts[node];
  const int* lp = csr_src + beg;
  float a0 = 0.f, a1 = 0.f, a2 = 0.f, a3 = 0.f;
  for (int base = 0; base < cnt; base += 64) {
    int rem = cnt - base;
    int m = rem < 64 ? rem : 64;
    int idx = lp[base + (lane < m ? lane : m - 1)];
    int mfull = m & ~15;
    int j = 0;
    for (; j < mfull; j += 16) {   // 16 edges per iter, 8 wide loads in flight
      if (C == 128) {
        float4 v[8];
        #pragma unroll
        for (int u = 0; u < 8; ++u) {
          int s = __shfl(idx, j + 2 * u + half);
          v[u] = *reinterpret_cast<const float4*>(h + (size_t)s * 128 + l5 * 4);
        }
        #pragma unroll
        for (int u = 0; u < 8; ++u) { a0 += v[u].x; a1 += v[u].y; a2 += v[u].z; a3 += v[u].w; }
      } else {
        float2 v[8];
        #pragma unroll
        for (int u = 0; u < 8; ++u) {
          int s = __shfl(idx, j + 2 * u + half);
          v[u] = *reinterpret_cast<const float2*>(h + (size_t)s * 64 + l5 * 2);
        }
        #pragma unroll
        for (int u = 0; u < 8; ++u) { a0 += v[u].x; a1 += v[u].y; }
      }
    }
    if (j < m) {  // tail: <16 edges, clamped loads + masked accumulate
      if (C == 128) {
        float4 v[8];
        #pragma unroll
        for (int u = 0; u < 8; ++u) {
          int ed = j + 2 * u + half;
          int s = __shfl(idx, ed < m ? ed : m - 1);
          v[u] = *reinterpret_cast<const float4*>(h + (size_t)s * 128 + l5 * 4);
        }
        #pragma unroll
        for (int u = 0; u < 8; ++u) {
          bool ok = (j + 2 * u + half) < m;
          a0 += ok ? v[u].x : 0.f;
          a1 += ok ? v[u].y : 0.f;
          a2 += ok ? v[u].z : 0.f;
          a3 += ok ? v[u].w : 0.f;
        }
      } else {
        float2 v[8];
        #pragma unroll
        for (int u = 0; u < 8; ++u) {
          int ed = j + 2 * u + half;
          int s = __shfl(idx, ed < m ? ed : m - 1);
          v[u] = *reinterpret_cast<const float2*>(h + (size_t)s * 64 + l5 * 2);
        }
        #pragma unroll
        for (int u = 0; u < 8; ++u) {
          bool ok = (j + 2 * u + half) < m;
          a0 += ok ? v[u].x : 0.f;
          a1 += ok ? v[u].y : 0.f;
        }
      }
    }
  }
  // combine even/odd halves
  a0 += __shfl_xor(a0, 32);
  a1 += __shfl_xor(a1, 32);
  if (C == 128) { a2 += __shfl_xor(a2, 32); a3 += __shfl_xor(a3, 32); }
  const float inv = 1.0f / sqrtf(1.0f + 1.0e-3f);
  if (half == 0) {
    if (C == 128) {
      float4 g = reinterpret_cast<const float4*>(gamma)[l5];
      float4 b = reinterpret_cast<const float4*>(beta)[l5];
      float4 o;
      o.x = fmaxf(fmaf(a0, g.x * inv, b.x), 0.f);
      o.y = fmaxf(fmaf(a1, g.y * inv, b.y), 0.f);
      o.z = fmaxf(fmaf(a2, g.z * inv, b.z), 0.f);
      o.w = fmaxf(fmaf(a3, g.w * inv, b.w), 0.f);
      *reinterpret_cast<float4*>(out + (size_t)node * 128 + l5 * 4) = o;
    } else {
      float2 g = reinterpret_cast<const float2*>(gamma)[l5];
      float2 b = reinterpret_cast<const float2*>(beta)[l5];
      float2 o;
      o.x = fmaxf(fmaf(a0, g.x * inv, b.x), 0.f);
      o.y = fmaxf(fmaf(a1, g.y * inv, b.y), 0.f);
      *reinterpret_cast<float2*>(out + (size_t)node * 64 + l5 * 2) = o;
    }
  }
}

// ---------------- Segment mean pool (seg sorted): p[64,64] ----------------

__global__ __launch_bounds__(1024) void pool_kernel(const float* __restrict__ h,
                                                    const int* __restrict__ seg,
                                                    float* __restrict__ p, int n) {
  int g = blockIdx.x;
  int lo, hi;
  { int l = 0, r = n; while (l < r) { int m = (l + r) >> 1; if (seg[m] < g) l = m + 1; else r = m; } lo = l; }
  { int l = 0, r = n; while (l < r) { int m = (l + r) >> 1; if (seg[m] < g + 1) l = m + 1; else r = m; } hi = l; }
  int c = threadIdx.x & 63;
  int sub = threadIdx.x >> 6;
  float acc = 0.f;
  for (int i = lo + sub; i < hi; i += 16) acc += h[(size_t)i * 64 + c];
  __shared__ float red[16][64];
  red[sub][c] = acc;
  __syncthreads();
  if (sub == 0) {
    float s = 0.f;
    #pragma unroll
    for (int k = 0; k < 16; ++k) s += red[k][c];
    float cnt = (float)(hi - lo);
    p[g * 64 + c] = s / fmaxf(cnt, 1.0f);
  }
}

// ---------------- Head: concat -> 2x Dense(128,relu, shared W) -> sigmoid ----------------

__global__ __launch_bounds__(512) void head_kernel(const float* __restrict__ p,
                                                   const float* __restrict__ Wd,
                                                   const float* __restrict__ bd,
                                                   const float* __restrict__ Wo,
                                                   const float* __restrict__ bo,
                                                   float* __restrict__ out) {
  __shared__ float cur[64][128];
  __shared__ float nxt[64][128];
  int tid = threadIdx.x;
  const float* p1 = p;
  const float* p2 = p + 64 * 64;
  for (int i = tid; i < 64 * 128; i += 512) {
    int r = i >> 7, c = i & 127;
    cur[r][c] = (c < 64) ? p1[r * 64 + c] : p2[r * 64 + (c - 64)];
  }
  __syncthreads();
  int c0 = (tid & 31) * 4;
  int r0 = (tid >> 5) * 4;
  for (int layer = 0; layer < 2; ++layer) {
    float acc[4][4] = {};
    #pragma unroll 4
    for (int k = 0; k < 128; ++k) {
      float4 w = *reinterpret_cast<const float4*>(&Wd[k * 128 + c0]);
      #pragma unroll
      for (int i = 0; i < 4; ++i) {
        float x = cur[r0 + i][k];
        acc[i][0] = fmaf(x, w.x, acc[i][0]);
        acc[i][1] = fmaf(x, w.y, acc[i][1]);
        acc[i][2] = fmaf(x, w.z, acc[i][2]);
        acc[i][3] = fmaf(x, w.w, acc[i][3]);
      }
    }
    float4 bv = *reinterpret_cast<const float4*>(&bd[c0]);
    __syncthreads();
    #pragma unroll
    for (int i = 0; i < 4; ++i) {
      float4 o;
      o.x = fmaxf(acc[i][0] + bv.x, 0.f);
      o.y = fmaxf(acc[i][1] + bv.y, 0.f);
      o.z = fmaxf(acc[i][2] + bv.z, 0.f);
      o.w = fmaxf(acc[i][3] + bv.w, 0.f);
      *reinterpret_cast<float4*>(&nxt[r0 + i][c0]) = o;
    }
    __syncthreads();
    for (int i = tid; i < 64 * 128; i += 512) (&cur[0][0])[i] = (&nxt[0][0])[i];
    __syncthreads();
  }
  int wv = tid >> 6, lane = tid & 63;
  for (int r = wv; r < 64; r += 8) {
    float v = cur[r][lane] * Wo[lane] + cur[r][64 + lane] * Wo[64 + lane];
    #pragma unroll
    for (int off = 32; off; off >>= 1) v += __shfl_down(v, off);
    if (lane == 0) out[r] = 1.0f / (1.0f + expf(-(v + bo[0])));
  }
}

// ---------------- launch ----------------

extern "C" void kernel_launch(void* const* d_in, const int* in_sizes, int n_in,
                              void* d_out, int out_size, void* d_ws, size_t ws_size,
                              hipStream_t stream) {
  const float* x1  = (const float*)d_in[0];
  const float* x2  = (const float*)d_in[1];
  const int* e1    = (const int*)d_in[2];
  const int* e2    = (const int*)d_in[3];
  const int* seg1  = (const int*)d_in[4];
  const int* seg2  = (const int*)d_in[5];
  const float* W1a = (const float*)d_in[6];  const float* b1a = (const float*)d_in[7];
  const float* g1a = (const float*)d_in[8];  const float* be1a = (const float*)d_in[9];
  const float* W1b = (const float*)d_in[10]; const float* b1b = (const float*)d_in[11];
  const float* g1b = (const float*)d_in[12]; const float* be1b = (const float*)d_in[13];
  const float* W2a = (const float*)d_in[14]; const float* b2a = (const float*)d_in[15];
  const float* g2a = (const float*)d_in[16]; const float* be2a = (const float*)d_in[17];
  const float* W2b = (const float*)d_in[18]; const float* b2b = (const float*)d_in[19];
  const float* g2b = (const float*)d_in[20]; const float* be2b = (const float*)d_in[21];
  const float* Wd  = (const float*)d_in[22]; const float* bd  = (const float*)d_in[23];
  const float* Wo  = (const float*)d_in[24]; const float* bo  = (const float*)d_in[25];
  float* out = (float*)d_out;

  const int N = in_sizes[0] / 128;
  const int E = in_sizes[2] / 2;

  char* ws = (char*)d_ws;
  size_t off = 0;
  auto alloc = [&](size_t bytes) -> void* {
    void* ptr = ws + off;
    off += (bytes + 255) & ~(size_t)255;
    return ptr;
  };
  float* h    = (float*)alloc((size_t)N * 128 * sizeof(float));
  float* aggb = (float*)alloc((size_t)N * 128 * sizeof(float));
  // [counts 2N][gcur 1] -> one small memset; cursor/offs fully written by alloc_kernel
  int* counts = (int*)alloc((size_t)(2 * N + 1) * sizeof(int));
  int* gcur   = counts + 2 * N;
  int* cursor = (int*)alloc((size_t)(2 * N) * sizeof(int));
  int* offs   = (int*)alloc((size_t)(2 * N) * sizeof(int));
  int* csr    = (int*)alloc((size_t)(2 * E) * sizeof(int));
  float* pbuf = (float*)alloc(2 * 64 * 64 * sizeof(float));
  (void)ws_size; (void)n_in; (void)out_size;

  // ---- CSR build for both branches up-front ----
  hipMemsetAsync(counts, 0, (size_t)(2 * N + 1) * sizeof(int), stream);
  {
    dim3 g((E + 255) / 256, 2);
    hist2_kernel<<<g, 256, 0, stream>>>(e1 + E, e2 + E, counts, E, N);
    alloc_kernel<<<(2 * N + 255) / 256, 256, 0, stream>>>(counts, offs, cursor, gcur, 2 * N);
    fill2_kernel<<<g, 256, 0, stream>>>(e1, e1 + E, e2, e2 + E, cursor, csr, E, N);
  }

  struct Branch {
    const float *x; const int *seg;
    const float *Wa, *ba, *ga, *bea, *Wb, *bb, *gb, *beb;
  };
  Branch brs[2] = {
    {x1, seg1, W1a, b1a, g1a, be1a, W1b, b1b, g1b, be1b},
    {x2, seg2, W2a, b2a, g2a, be2a, W2b, b2b, g2b, be2b},
  };

  for (int b = 0; b < 2; ++b) {
    const int* offs_b = offs + b * N;
    const int* cnts_b = counts + b * N;
    gemm_kernel<128><<<(N + 63) / 64, 256, 0, stream>>>(brs[b].x, brs[b].Wa, brs[b].ba, h, N);
    agg_kernel<128><<<(N + 3) / 4, 256, 0, stream>>>(h, offs_b, cnts_b, csr, brs[b].ga, brs[b].bea, aggb, N);
    gemm_kernel<64><<<(N + 63) / 64, 256, 0, stream>>>(aggb, brs[b].Wb, brs[b].bb, h, N);
    agg_kernel<64><<<(N + 3) / 4, 256, 0, stream>>>(h, offs_b, cnts_b, csr, brs[b].gb, brs[b].beb, aggb, N);
    pool_kernel<<<64, 1024, 0, stream>>>(aggb, brs[b].seg, pbuf + b * 64 * 64, N);
  }
  head_kernel<<<1, 512, 0, stream>>>(pbuf, Wd, bd, Wo, bo, out);
}

// Round 8
// 424.308 us; speedup vs baseline: 5.7601x; 1.2848x over previous
//
#include <hip/hip_runtime.h>
#include <math.h>

#define GS   4096   // nodes per coarse group
#define GSH  12
#define NGMAX 16    // max coarse groups per branch (G1=13 for N=50000)
#define FCAP 256    // LDS FIFO capacity per group per round

// ---------------- pass 1: bin edges into coarse groups (dense chunked writes) ----------------
// pk = src | (d_local << 17)   (src < 2^17, d_local < 4096)

__global__ __launch_bounds__(1024) void bin_kernel(
    const int* __restrict__ s1, const int* __restrict__ d1,
    const int* __restrict__ s2, const int* __restrict__ d2,
    int* __restrict__ gcur, int* __restrict__ pairs, int E, int G1, int CAP) {
  __shared__ int fifo[NGMAX][FCAP];
  __shared__ int fcnt[NGMAX];
  __shared__ int fbase[NGMAX];
  __shared__ int fpre[NGMAX + 1];
  const int* src = blockIdx.y ? s2 : s1;
  const int* dst = blockIdx.y ? d2 : d1;
  int gboff = blockIdx.y * G1;
  int tid = threadIdx.x;
  if (tid < NGMAX) fcnt[tid] = 0;
  __syncthreads();
  int e0 = blockIdx.x * 4096;
  for (int r = 0; r < 4; ++r) {
    int e = e0 + r * 1024 + tid;
    if (e < E) {
      int s = src[e], d = dst[e];
      int g = d >> GSH;
      int pk = s | ((d & (GS - 1)) << 17);
      int pos = atomicAdd(&fcnt[g], 1);
      if (pos < FCAP) fifo[g][pos] = pk;
      else {  // statistically never: direct append
        int gp = atomicAdd(&gcur[gboff + g], 1);
        pairs[(size_t)(gboff + g) * CAP + gp] = pk;
      }
    }
    __syncthreads();
    if (tid < G1) {
      int c = fcnt[tid];
      if (c > FCAP) c = FCAP;
      fcnt[tid] = c;
      fbase[tid] = (c > 0) ? atomicAdd(&gcur[gboff + tid], c) : 0;
    }
    __syncthreads();
    if (tid == 0) {
      int acc = 0;
      for (int i = 0; i < G1; ++i) { fpre[i] = acc; acc += fcnt[i]; }
      fpre[G1] = acc;
    }
    __syncthreads();
    int T = fpre[G1];
    for (int t = tid; t < T; t += 1024) {
      int g2 = 0;
      while (fpre[g2 + 1] <= t) ++g2;
      int idx = t - fpre[g2];
      pairs[(size_t)(gboff + g2) * CAP + fbase[g2] + idx] = fifo[g2][idx];
    }
    __syncthreads();
    if (tid < NGMAX) fcnt[tid] = 0;
    __syncthreads();
  }
}

// ---------------- pass 2: per-group node-level CSR (all RMW traffic XCD-local) ----------------

__global__ __launch_bounds__(1024) void refine_kernel(
    const int* __restrict__ pairs, const int* __restrict__ gcur,
    int* __restrict__ csr, int* __restrict__ offs, int* __restrict__ counts,
    int N, int G1, int CAP) {
  __shared__ int hist[GS];   // 16KB
  __shared__ int excl[GS];   // 16KB (becomes cursor in scatter)
  __shared__ int wsum[1024]; // 4KB
  int gl = blockIdx.x, br = blockIdx.y;
  int g = br * G1 + gl;
  size_t rbase = (size_t)g * CAP;
  int rcnt = gcur[g];
  int tid = threadIdx.x;
  for (int i = tid; i < GS; i += 1024) hist[i] = 0;
  __syncthreads();
  for (int i = tid; i < rcnt; i += 1024) atomicAdd(&hist[pairs[rbase + i] >> 17], 1);
  __syncthreads();
  int b4 = tid * 4;
  int h0 = hist[b4], h1 = hist[b4 + 1], h2 = hist[b4 + 2], h3 = hist[b4 + 3];
  int s = h0 + h1 + h2 + h3;
  wsum[tid] = s;
  __syncthreads();
  for (int off = 1; off < 1024; off <<= 1) {
    int t = (tid >= off) ? wsum[tid - off] : 0;
    __syncthreads();
    wsum[tid] += t;
    __syncthreads();
  }
  int eb = wsum[tid] - s;
  excl[b4] = eb;
  excl[b4 + 1] = eb + h0;
  excl[b4 + 2] = eb + h0 + h1;
  excl[b4 + 3] = eb + h0 + h1 + h2;
  __syncthreads();
  int node0 = gl * GS;
  int nloc = N - node0; if (nloc > GS) nloc = GS;
  for (int j = tid; j < nloc; j += 1024) {
    offs[br * N + node0 + j] = (int)rbase + excl[j];
    counts[br * N + node0 + j] = hist[j];
  }
  __syncthreads();
  for (int i = tid; i < rcnt; i += 1024) {
    int pk = pairs[rbase + i];
    int pos = atomicAdd(&excl[pk >> 17], 1);
    csr[rbase + pos] = pk & 0x1FFFF;
  }
}

// ---------------- GEMM: Y[nrows,COUT] = X[nrows,128] @ W[128,COUT] + bias ----------------

template <int COUT>
__global__ __launch_bounds__(256, 2) void gemm_kernel(const float* __restrict__ X,
                                                      const float* __restrict__ W,
                                                      const float* __restrict__ bias,
                                                      float* __restrict__ Y, int nrows) {
  constexpr int CG = COUT / 4;
  constexpr int RG = 256 / CG;
  constexpr int BM = 64;
  constexpr int RPT = BM / RG;
  __shared__ float xs[BM][132];
  int tid = threadIdx.x;
  int block_row = blockIdx.x * BM;
  for (int i = tid; i < BM * 32; i += 256) {
    int r = i >> 5, c4 = i & 31;
    int gr = block_row + r;
    float4 v = make_float4(0.f, 0.f, 0.f, 0.f);
    if (gr < nrows) v = reinterpret_cast<const float4*>(X + (size_t)gr * 128)[c4];
    *reinterpret_cast<float4*>(&xs[r][c4 * 4]) = v;
  }
  __syncthreads();
  int c0 = (tid % CG) * 4;
  int r0 = (tid / CG) * RPT;
  float acc[RPT][4] = {};
  #pragma unroll 2
  for (int k = 0; k < 128; k += 4) {
    float4 w0 = *reinterpret_cast<const float4*>(&W[(k + 0) * COUT + c0]);
    float4 w1 = *reinterpret_cast<const float4*>(&W[(k + 1) * COUT + c0]);
    float4 w2 = *reinterpret_cast<const float4*>(&W[(k + 2) * COUT + c0]);
    float4 w3 = *reinterpret_cast<const float4*>(&W[(k + 3) * COUT + c0]);
    #pragma unroll
    for (int i = 0; i < RPT; ++i) {
      float4 x = *reinterpret_cast<const float4*>(&xs[r0 + i][k]);
      acc[i][0] = fmaf(x.x, w0.x, acc[i][0]);
      acc[i][1] = fmaf(x.x, w0.y, acc[i][1]);
      acc[i][2] = fmaf(x.x, w0.z, acc[i][2]);
      acc[i][3] = fmaf(x.x, w0.w, acc[i][3]);
      acc[i][0] = fmaf(x.y, w1.x, acc[i][0]);
      acc[i][1] = fmaf(x.y, w1.y, acc[i][1]);
      acc[i][2] = fmaf(x.y, w1.z, acc[i][2]);
      acc[i][3] = fmaf(x.y, w1.w, acc[i][3]);
      acc[i][0] = fmaf(x.z, w2.x, acc[i][0]);
      acc[i][1] = fmaf(x.z, w2.y, acc[i][1]);
      acc[i][2] = fmaf(x.z, w2.z, acc[i][2]);
      acc[i][3] = fmaf(x.z, w2.w, acc[i][3]);
      acc[i][0] = fmaf(x.w, w3.x, acc[i][0]);
      acc[i][1] = fmaf(x.w, w3.y, acc[i][1]);
      acc[i][2] = fmaf(x.w, w3.z, acc[i][2]);
      acc[i][3] = fmaf(x.w, w3.w, acc[i][3]);
    }
  }
  float4 bv = *reinterpret_cast<const float4*>(&bias[c0]);
  #pragma unroll
  for (int i = 0; i < RPT; ++i) {
    int gr = block_row + r0 + i;
    if (gr < nrows) {
      float4 o;
      o.x = acc[i][0] + bv.x; o.y = acc[i][1] + bv.y;
      o.z = acc[i][2] + bv.z; o.w = acc[i][3] + bv.w;
      *reinterpret_cast<float4*>(&Y[(size_t)gr * COUT + c0]) = o;
    }
  }
}

// ---------------- Aggregate (CSR gather-sum) + BN(inference) + relu ----------------
// Wave per node, half-wave split: full row per wide load, even/odd edges per half.

template <int C>
__global__ __launch_bounds__(256) void agg_kernel(const float* __restrict__ h,
                                                  const int* __restrict__ offs,
                                                  const int* __restrict__ counts,
                                                  const int* __restrict__ csr_src,
                                                  const float* __restrict__ gamma,
                                                  const float* __restrict__ beta,
                                                  float* __restrict__ out, int n) {
  int node = blockIdx.x * 4 + (threadIdx.x >> 6);
  if (node >= n) return;
  node = __builtin_amdgcn_readfirstlane(node);
  int lane = threadIdx.x & 63;
  int half = lane >> 5;
  int l5 = lane & 31;
  int beg = offs[node], cnt = counts[node];
  const int* lp = csr_src + beg;
  float a0 = 0.f, a1 = 0.f, a2 = 0.f, a3 = 0.f;
  for (int base = 0; base < cnt; base += 64) {
    int rem = cnt - base;
    int m = rem < 64 ? rem : 64;
    int idx = lp[base + (lane < m ? lane : m - 1)];
    int mfull = m & ~15;
    int j = 0;
    for (; j < mfull; j += 16) {
      if (C == 128) {
        float4 v[8];
        #pragma unroll
        for (int u = 0; u < 8; ++u) {
          int s = __shfl(idx, j + 2 * u + half);
          v[u] = *reinterpret_cast<const float4*>(h + (size_t)s * 128 + l5 * 4);
        }
        #pragma unroll
        for (int u = 0; u < 8; ++u) { a0 += v[u].x; a1 += v[u].y; a2 += v[u].z; a3 += v[u].w; }
      } else {
        float2 v[8];
        #pragma unroll
        for (int u = 0; u < 8; ++u) {
          int s = __shfl(idx, j + 2 * u + half);
          v[u] = *reinterpret_cast<const float2*>(h + (size_t)s * 64 + l5 * 2);
        }
        #pragma unroll
        for (int u = 0; u < 8; ++u) { a0 += v[u].x; a1 += v[u].y; }
      }
    }
    if (j < m) {
      if (C == 128) {
        float4 v[8];
        #pragma unroll
        for (int u = 0; u < 8; ++u) {
          int ed = j + 2 * u + half;
          int s = __shfl(idx, ed < m ? ed : m - 1);
          v[u] = *reinterpret_cast<const float4*>(h + (size_t)s * 128 + l5 * 4);
        }
        #pragma unroll
        for (int u = 0; u < 8; ++u) {
          bool ok = (j + 2 * u + half) < m;
          a0 += ok ? v[u].x : 0.f;
          a1 += ok ? v[u].y : 0.f;
          a2 += ok ? v[u].z : 0.f;
          a3 += ok ? v[u].w : 0.f;
        }
      } else {
        float2 v[8];
        #pragma unroll
        for (int u = 0; u < 8; ++u) {
          int ed = j + 2 * u + half;
          int s = __shfl(idx, ed < m ? ed : m - 1);
          v[u] = *reinterpret_cast<const float2*>(h + (size_t)s * 64 + l5 * 2);
        }
        #pragma unroll
        for (int u = 0; u < 8; ++u) {
          bool ok = (j + 2 * u + half) < m;
          a0 += ok ? v[u].x : 0.f;
          a1 += ok ? v[u].y : 0.f;
        }
      }
    }
  }
  a0 += __shfl_xor(a0, 32);
  a1 += __shfl_xor(a1, 32);
  if (C == 128) { a2 += __shfl_xor(a2, 32); a3 += __shfl_xor(a3, 32); }
  const float inv = 1.0f / sqrtf(1.0f + 1.0e-3f);
  if (half == 0) {
    if (C == 128) {
      float4 g = reinterpret_cast<const float4*>(gamma)[l5];
      float4 b = reinterpret_cast<const float4*>(beta)[l5];
      float4 o;
      o.x = fmaxf(fmaf(a0, g.x * inv, b.x), 0.f);
      o.y = fmaxf(fmaf(a1, g.y * inv, b.y), 0.f);
      o.z = fmaxf(fmaf(a2, g.z * inv, b.z), 0.f);
      o.w = fmaxf(fmaf(a3, g.w * inv, b.w), 0.f);
      *reinterpret_cast<float4*>(out + (size_t)node * 128 + l5 * 4) = o;
    } else {
      float2 g = reinterpret_cast<const float2*>(gamma)[l5];
      float2 b = reinterpret_cast<const float2*>(beta)[l5];
      float2 o;
      o.x = fmaxf(fmaf(a0, g.x * inv, b.x), 0.f);
      o.y = fmaxf(fmaf(a1, g.y * inv, b.y), 0.f);
      *reinterpret_cast<float2*>(out + (size_t)node * 64 + l5 * 2) = o;
    }
  }
}

// ---------------- Segment mean pool (seg sorted): p[64,64] ----------------

__global__ __launch_bounds__(1024) void pool_kernel(const float* __restrict__ h,
                                                    const int* __restrict__ seg,
                                                    float* __restrict__ p, int n) {
  int g = blockIdx.x;
  int lo, hi;
  { int l = 0, r = n; while (l < r) { int m = (l + r) >> 1; if (seg[m] < g) l = m + 1; else r = m; } lo = l; }
  { int l = 0, r = n; while (l < r) { int m = (l + r) >> 1; if (seg[m] < g + 1) l = m + 1; else r = m; } hi = l; }
  int c = threadIdx.x & 63;
  int sub = threadIdx.x >> 6;
  float acc = 0.f;
  for (int i = lo + sub; i < hi; i += 16) acc += h[(size_t)i * 64 + c];
  __shared__ float red[16][64];
  red[sub][c] = acc;
  __syncthreads();
  if (sub == 0) {
    float s = 0.f;
    #pragma unroll
    for (int k = 0; k < 16; ++k) s += red[k][c];
    float cnt = (float)(hi - lo);
    p[g * 64 + c] = s / fmaxf(cnt, 1.0f);
  }
}

// ---------------- Head: concat -> 2x Dense(128,relu, shared W) -> sigmoid ----------------

__global__ __launch_bounds__(512) void head_kernel(const float* __restrict__ p,
                                                   const float* __restrict__ Wd,
                                                   const float* __restrict__ bd,
                                                   const float* __restrict__ Wo,
                                                   const float* __restrict__ bo,
                                                   float* __restrict__ out) {
  __shared__ float cur[64][128];
  __shared__ float nxt[64][128];
  int tid = threadIdx.x;
  const float* p1 = p;
  const float* p2 = p + 64 * 64;
  for (int i = tid; i < 64 * 128; i += 512) {
    int r = i >> 7, c = i & 127;
    cur[r][c] = (c < 64) ? p1[r * 64 + c] : p2[r * 64 + (c - 64)];
  }
  __syncthreads();
  int c0 = (tid & 31) * 4;
  int r0 = (tid >> 5) * 4;
  for (int layer = 0; layer < 2; ++layer) {
    float acc[4][4] = {};
    #pragma unroll 4
    for (int k = 0; k < 128; ++k) {
      float4 w = *reinterpret_cast<const float4*>(&Wd[k * 128 + c0]);
      #pragma unroll
      for (int i = 0; i < 4; ++i) {
        float x = cur[r0 + i][k];
        acc[i][0] = fmaf(x, w.x, acc[i][0]);
        acc[i][1] = fmaf(x, w.y, acc[i][1]);
        acc[i][2] = fmaf(x, w.z, acc[i][2]);
        acc[i][3] = fmaf(x, w.w, acc[i][3]);
      }
    }
    float4 bv = *reinterpret_cast<const float4*>(&bd[c0]);
    __syncthreads();
    #pragma unroll
    for (int i = 0; i < 4; ++i) {
      float4 o;
      o.x = fmaxf(acc[i][0] + bv.x, 0.f);
      o.y = fmaxf(acc[i][1] + bv.y, 0.f);
      o.z = fmaxf(acc[i][2] + bv.z, 0.f);
      o.w = fmaxf(acc[i][3] + bv.w, 0.f);
      *reinterpret_cast<float4*>(&nxt[r0 + i][c0]) = o;
    }
    __syncthreads();
    for (int i = tid; i < 64 * 128; i += 512) (&cur[0][0])[i] = (&nxt[0][0])[i];
    __syncthreads();
  }
  int wv = tid >> 6, lane = tid & 63;
  for (int r = wv; r < 64; r += 8) {
    float v = cur[r][lane] * Wo[lane] + cur[r][64 + lane] * Wo[64 + lane];
    #pragma unroll
    for (int off = 32; off; off >>= 1) v += __shfl_down(v, off);
    if (lane == 0) out[r] = 1.0f / (1.0f + expf(-(v + bo[0])));
  }
}

// ---------------- launch ----------------

extern "C" void kernel_launch(void* const* d_in, const int* in_sizes, int n_in,
                              void* d_out, int out_size, void* d_ws, size_t ws_size,
                              hipStream_t stream) {
  const float* x1  = (const float*)d_in[0];
  const float* x2  = (const float*)d_in[1];
  const int* e1    = (const int*)d_in[2];
  const int* e2    = (const int*)d_in[3];
  const int* seg1  = (const int*)d_in[4];
  const int* seg2  = (const int*)d_in[5];
  const float* W1a = (const float*)d_in[6];  const float* b1a = (const float*)d_in[7];
  const float* g1a = (const float*)d_in[8];  const float* be1a = (const float*)d_in[9];
  const float* W1b = (const float*)d_in[10]; const float* b1b = (const float*)d_in[11];
  const float* g1b = (const float*)d_in[12]; const float* be1b = (const float*)d_in[13];
  const float* W2a = (const float*)d_in[14]; const float* b2a = (const float*)d_in[15];
  const float* g2a = (const float*)d_in[16]; const float* be2a = (const float*)d_in[17];
  const float* W2b = (const float*)d_in[18]; const float* b2b = (const float*)d_in[19];
  const float* g2b = (const float*)d_in[20]; const float* be2b = (const float*)d_in[21];
  const float* Wd  = (const float*)d_in[22]; const float* bd  = (const float*)d_in[23];
  const float* Wo  = (const float*)d_in[24]; const float* bo  = (const float*)d_in[25];
  float* out = (float*)d_out;

  const int N = in_sizes[0] / 128;
  const int E = in_sizes[2] / 2;
  const int G1 = (N + GS - 1) >> GSH;                       // coarse groups per branch
  const int G  = 2 * G1;
  // region capacity: mean edges per full group + ~8-sigma cushion, 512-aligned
  const int CAP = (int)((((long long)E * GS / N) + 2048 + 511) & ~511LL);

  char* ws = (char*)d_ws;
  size_t off = 0;
  auto alloc = [&](size_t bytes) -> void* {
    void* ptr = ws + off;
    off += (bytes + 255) & ~(size_t)255;
    return ptr;
  };
  float* h    = (float*)alloc((size_t)N * 128 * sizeof(float));
  float* aggb = (float*)alloc((size_t)N * 128 * sizeof(float));
  int* pairs  = (int*)alloc((size_t)G * CAP * sizeof(int));
  int* csr    = (int*)alloc((size_t)G * CAP * sizeof(int));
  int* offs   = (int*)alloc((size_t)(2 * N) * sizeof(int));
  int* counts = (int*)alloc((size_t)(2 * N) * sizeof(int));
  int* gcur   = (int*)alloc((size_t)(G + 8) * sizeof(int));
  float* pbuf = (float*)alloc(2 * 64 * 64 * sizeof(float));
  (void)ws_size; (void)n_in; (void)out_size;

  // ---- CSR build: coarse bin (dense chunked writes) + per-group refine (XCD-local) ----
  hipMemsetAsync(gcur, 0, (size_t)(G + 8) * sizeof(int), stream);
  {
    dim3 gb((E + 4095) / 4096, 2);
    bin_kernel<<<gb, 1024, 0, stream>>>(e1, e1 + E, e2, e2 + E, gcur, pairs, E, G1, CAP);
    dim3 gr(G1, 2);
    refine_kernel<<<gr, 1024, 0, stream>>>(pairs, gcur, csr, offs, counts, N, G1, CAP);
  }

  struct Branch {
    const float *x; const int *seg;
    const float *Wa, *ba, *ga, *bea, *Wb, *bb, *gb, *beb;
  };
  Branch brs[2] = {
    {x1, seg1, W1a, b1a, g1a, be1a, W1b, b1b, g1b, be1b},
    {x2, seg2, W2a, b2a, g2a, be2a, W2b, b2b, g2b, be2b},
  };

  for (int b = 0; b < 2; ++b) {
    const int* offs_b = offs + b * N;
    const int* cnts_b = counts + b * N;
    gemm_kernel<128><<<(N + 63) / 64, 256, 0, stream>>>(brs[b].x, brs[b].Wa, brs[b].ba, h, N);
    agg_kernel<128><<<(N + 3) / 4, 256, 0, stream>>>(h, offs_b, cnts_b, csr, brs[b].ga, brs[b].bea, aggb, N);
    gemm_kernel<64><<<(N + 63) / 64, 256, 0, stream>>>(aggb, brs[b].Wb, brs[b].bb, h, N);
    agg_kernel<64><<<(N + 3) / 4, 256, 0, stream>>>(h, offs_b, cnts_b, csr, brs[b].gb, brs[b].beb, aggb, N);
    pool_kernel<<<64, 1024, 0, stream>>>(aggb, brs[b].seg, pbuf + b * 64 * 64, N);
  }
  head_kernel<<<1, 512, 0, stream>>>(pbuf, Wd, bd, Wo, bo, out);
}

// Round 9
// 380.128 us; speedup vs baseline: 6.4296x; 1.1162x over previous
//
#include <hip/hip_runtime.h>
#include <math.h>

#define GS    512   // nodes per group
#define GSH   9
#define NGMAX 128   // max groups per branch (G1=98 for N=50000)
#define FCAP  48    // LDS FIFO capacity per group per round (mean ~10.5)
#define SCAP  10240 // group region capacity (mean 8192 + 2048 cushion, 512-aligned)

// ---------------- pass 1: bin edges into 512-node groups (dense chunked writes) ----------------
// pk = src | (d_local << 17)   (src < 2^17, d_local < 512)

__global__ __launch_bounds__(1024) void bin_kernel(
    const int* __restrict__ s1, const int* __restrict__ d1,
    const int* __restrict__ s2, const int* __restrict__ d2,
    int* __restrict__ gcur, int* __restrict__ pairs, int E, int G1) {
  __shared__ int fifo[NGMAX][FCAP];
  __shared__ int fcnt[NGMAX];
  __shared__ int fbase[NGMAX];
  __shared__ int fpre[NGMAX + 1];
  const int* src = blockIdx.y ? s2 : s1;
  const int* dst = blockIdx.y ? d2 : d1;
  int gboff = blockIdx.y * G1;
  int tid = threadIdx.x;
  if (tid < NGMAX) fcnt[tid] = 0;
  __syncthreads();
  int e0 = blockIdx.x * 4096;
  for (int r = 0; r < 4; ++r) {
    int e = e0 + r * 1024 + tid;
    if (e < E) {
      int s = src[e], d = dst[e];
      int g = d >> GSH;
      int pk = s | ((d & (GS - 1)) << 17);
      int pos = atomicAdd(&fcnt[g], 1);
      if (pos < FCAP) fifo[g][pos] = pk;
      else {  // statistically never: direct append
        int gp = atomicAdd(&gcur[gboff + g], 1);
        pairs[(size_t)(gboff + g) * SCAP + gp] = pk;
      }
    }
    __syncthreads();
    if (tid < G1) {
      int c = fcnt[tid];
      if (c > FCAP) c = FCAP;
      fcnt[tid] = c;
      fbase[tid] = (c > 0) ? atomicAdd(&gcur[gboff + tid], c) : 0;
    }
    __syncthreads();
    if (tid == 0) {
      int acc = 0;
      for (int i = 0; i < G1; ++i) { fpre[i] = acc; acc += fcnt[i]; }
      fpre[G1] = acc;
    }
    __syncthreads();
    int T = fpre[G1];
    for (int t = tid; t < T; t += 1024) {
      int lo = 0, hi = G1;              // binary search: fpre[lo] <= t < fpre[lo+1]
      while (hi - lo > 1) { int mid = (lo + hi) >> 1; if (fpre[mid] <= t) lo = mid; else hi = mid; }
      int idx = t - fpre[lo];
      pairs[(size_t)(gboff + lo) * SCAP + fbase[lo] + idx] = fifo[lo][idx];
    }
    __syncthreads();
    if (tid < NGMAX) fcnt[tid] = 0;
    __syncthreads();
  }
}

// ---------------- pass 2: per-group node CSR, in-place (stage -> hist -> scan -> scatter) ----------------

__global__ __launch_bounds__(1024) void refine_kernel(
    const int* __restrict__ gcur, int* __restrict__ pairs,
    int* __restrict__ offs, int* __restrict__ counts, int N, int G1) {
  __shared__ int stg[SCAP];   // 40KB
  __shared__ int hist[GS];
  __shared__ int excl[GS];
  __shared__ int wtot[8];
  int gl = blockIdx.x, br = blockIdx.y;
  int g = br * G1 + gl;
  size_t rbase = (size_t)g * SCAP;
  int rcnt = gcur[g];
  if (rcnt > SCAP) rcnt = SCAP;
  int tid = threadIdx.x;
  if (tid < GS) hist[tid] = 0;
  __syncthreads();
  for (int i = tid; i < rcnt; i += 1024) {
    int pk = pairs[rbase + i];
    stg[i] = pk;
    atomicAdd(&hist[pk >> 17], 1);
  }
  __syncthreads();
  // exclusive scan over 512 bins: 8 wave scans + cross-wave offsets
  if (tid < GS) {
    int lane = tid & 63, wv = tid >> 6;
    int v = hist[tid];
    int inc = v;
    #pragma unroll
    for (int off = 1; off < 64; off <<= 1) {
      int t = __shfl_up(inc, off);
      if (lane >= off) inc += t;
    }
    excl[tid] = inc - v;
    if (lane == 63) wtot[wv] = inc;
  }
  __syncthreads();
  if (tid == 0) {
    int a = 0;
    #pragma unroll
    for (int w = 0; w < 8; ++w) { int t = wtot[w]; wtot[w] = a; a += t; }
  }
  __syncthreads();
  if (tid < GS) excl[tid] += wtot[tid >> 6];
  __syncthreads();
  int node0 = gl * GS;
  int nloc = N - node0; if (nloc > GS) nloc = GS;
  for (int j = tid; j < nloc; j += 1024) {
    offs[br * N + node0 + j] = (int)rbase + excl[j];
    counts[br * N + node0 + j] = hist[j];
  }
  __syncthreads();
  for (int i = tid; i < rcnt; i += 1024) {
    int pk = stg[i];
    int pos = atomicAdd(&excl[pk >> 17], 1);
    pairs[rbase + pos] = pk & 0x1FFFF;   // in-place: pairs becomes csr
  }
}

// ---------------- GEMM: Y[nrows,COUT] = X[nrows,128] @ W[128,COUT] + bias ----------------

template <int COUT>
__global__ __launch_bounds__(256, 2) void gemm_kernel(const float* __restrict__ X,
                                                      const float* __restrict__ W,
                                                      const float* __restrict__ bias,
                                                      float* __restrict__ Y, int nrows) {
  constexpr int CG = COUT / 4;
  constexpr int RG = 256 / CG;
  constexpr int BM = 64;
  constexpr int RPT = BM / RG;
  __shared__ float xs[BM][132];
  int tid = threadIdx.x;
  int block_row = blockIdx.x * BM;
  for (int i = tid; i < BM * 32; i += 256) {
    int r = i >> 5, c4 = i & 31;
    int gr = block_row + r;
    float4 v = make_float4(0.f, 0.f, 0.f, 0.f);
    if (gr < nrows) v = reinterpret_cast<const float4*>(X + (size_t)gr * 128)[c4];
    *reinterpret_cast<float4*>(&xs[r][c4 * 4]) = v;
  }
  __syncthreads();
  int c0 = (tid % CG) * 4;
  int r0 = (tid / CG) * RPT;
  float acc[RPT][4] = {};
  #pragma unroll 2
  for (int k = 0; k < 128; k += 4) {
    float4 w0 = *reinterpret_cast<const float4*>(&W[(k + 0) * COUT + c0]);
    float4 w1 = *reinterpret_cast<const float4*>(&W[(k + 1) * COUT + c0]);
    float4 w2 = *reinterpret_cast<const float4*>(&W[(k + 2) * COUT + c0]);
    float4 w3 = *reinterpret_cast<const float4*>(&W[(k + 3) * COUT + c0]);
    #pragma unroll
    for (int i = 0; i < RPT; ++i) {
      float4 x = *reinterpret_cast<const float4*>(&xs[r0 + i][k]);
      acc[i][0] = fmaf(x.x, w0.x, acc[i][0]);
      acc[i][1] = fmaf(x.x, w0.y, acc[i][1]);
      acc[i][2] = fmaf(x.x, w0.z, acc[i][2]);
      acc[i][3] = fmaf(x.x, w0.w, acc[i][3]);
      acc[i][0] = fmaf(x.y, w1.x, acc[i][0]);
      acc[i][1] = fmaf(x.y, w1.y, acc[i][1]);
      acc[i][2] = fmaf(x.y, w1.z, acc[i][2]);
      acc[i][3] = fmaf(x.y, w1.w, acc[i][3]);
      acc[i][0] = fmaf(x.z, w2.x, acc[i][0]);
      acc[i][1] = fmaf(x.z, w2.y, acc[i][1]);
      acc[i][2] = fmaf(x.z, w2.z, acc[i][2]);
      acc[i][3] = fmaf(x.z, w2.w, acc[i][3]);
      acc[i][0] = fmaf(x.w, w3.x, acc[i][0]);
      acc[i][1] = fmaf(x.w, w3.y, acc[i][1]);
      acc[i][2] = fmaf(x.w, w3.z, acc[i][2]);
      acc[i][3] = fmaf(x.w, w3.w, acc[i][3]);
    }
  }
  float4 bv = *reinterpret_cast<const float4*>(&bias[c0]);
  #pragma unroll
  for (int i = 0; i < RPT; ++i) {
    int gr = block_row + r0 + i;
    if (gr < nrows) {
      float4 o;
      o.x = acc[i][0] + bv.x; o.y = acc[i][1] + bv.y;
      o.z = acc[i][2] + bv.z; o.w = acc[i][3] + bv.w;
      *reinterpret_cast<float4*>(&Y[(size_t)gr * COUT + c0]) = o;
    }
  }
}

// ---------------- Aggregate (CSR gather-sum) + BN(inference) + relu ----------------

template <int C>
__global__ __launch_bounds__(256) void agg_kernel(const float* __restrict__ h,
                                                  const int* __restrict__ offs,
                                                  const int* __restrict__ counts,
                                                  const int* __restrict__ csr_src,
                                                  const float* __restrict__ gamma,
                                                  const float* __restrict__ beta,
                                                  float* __restrict__ out, int n) {
  int node = blockIdx.x * 4 + (threadIdx.x >> 6);
  if (node >= n) return;
  node = __builtin_amdgcn_readfirstlane(node);
  int lane = threadIdx.x & 63;
  int half = lane >> 5;
  int l5 = lane & 31;
  int beg = offs[node], cnt = counts[node];
  const int* lp = csr_src + beg;
  float a0 = 0.f, a1 = 0.f, a2 = 0.f, a3 = 0.f;
  for (int base = 0; base < cnt; base += 64) {
    int rem = cnt - base;
    int m = rem < 64 ? rem : 64;
    int idx = lp[base + (lane < m ? lane : m - 1)];
    int mfull = m & ~15;
    int j = 0;
    for (; j < mfull; j += 16) {
      if (C == 128) {
        float4 v[8];
        #pragma unroll
        for (int u = 0; u < 8; ++u) {
          int s = __shfl(idx, j + 2 * u + half);
          v[u] = *reinterpret_cast<const float4*>(h + (size_t)s * 128 + l5 * 4);
        }
        #pragma unroll
        for (int u = 0; u < 8; ++u) { a0 += v[u].x; a1 += v[u].y; a2 += v[u].z; a3 += v[u].w; }
      } else {
        float2 v[8];
        #pragma unroll
        for (int u = 0; u < 8; ++u) {
          int s = __shfl(idx, j + 2 * u + half);
          v[u] = *reinterpret_cast<const float2*>(h + (size_t)s * 64 + l5 * 2);
        }
        #pragma unroll
        for (int u = 0; u < 8; ++u) { a0 += v[u].x; a1 += v[u].y; }
      }
    }
    if (j < m) {
      if (C == 128) {
        float4 v[8];
        #pragma unroll
        for (int u = 0; u < 8; ++u) {
          int ed = j + 2 * u + half;
          int s = __shfl(idx, ed < m ? ed : m - 1);
          v[u] = *reinterpret_cast<const float4*>(h + (size_t)s * 128 + l5 * 4);
        }
        #pragma unroll
        for (int u = 0; u < 8; ++u) {
          bool ok = (j + 2 * u + half) < m;
          a0 += ok ? v[u].x : 0.f;
          a1 += ok ? v[u].y : 0.f;
          a2 += ok ? v[u].z : 0.f;
          a3 += ok ? v[u].w : 0.f;
        }
      } else {
        float2 v[8];
        #pragma unroll
        for (int u = 0; u < 8; ++u) {
          int ed = j + 2 * u + half;
          int s = __shfl(idx, ed < m ? ed : m - 1);
          v[u] = *reinterpret_cast<const float2*>(h + (size_t)s * 64 + l5 * 2);
        }
        #pragma unroll
        for (int u = 0; u < 8; ++u) {
          bool ok = (j + 2 * u + half) < m;
          a0 += ok ? v[u].x : 0.f;
          a1 += ok ? v[u].y : 0.f;
        }
      }
    }
  }
  a0 += __shfl_xor(a0, 32);
  a1 += __shfl_xor(a1, 32);
  if (C == 128) { a2 += __shfl_xor(a2, 32); a3 += __shfl_xor(a3, 32); }
  const float inv = 1.0f / sqrtf(1.0f + 1.0e-3f);
  if (half == 0) {
    if (C == 128) {
      float4 g = reinterpret_cast<const float4*>(gamma)[l5];
      float4 b = reinterpret_cast<const float4*>(beta)[l5];
      float4 o;
      o.x = fmaxf(fmaf(a0, g.x * inv, b.x), 0.f);
      o.y = fmaxf(fmaf(a1, g.y * inv, b.y), 0.f);
      o.z = fmaxf(fmaf(a2, g.z * inv, b.z), 0.f);
      o.w = fmaxf(fmaf(a3, g.w * inv, b.w), 0.f);
      *reinterpret_cast<float4*>(out + (size_t)node * 128 + l5 * 4) = o;
    } else {
      float2 g = reinterpret_cast<const float2*>(gamma)[l5];
      float2 b = reinterpret_cast<const float2*>(beta)[l5];
      float2 o;
      o.x = fmaxf(fmaf(a0, g.x * inv, b.x), 0.f);
      o.y = fmaxf(fmaf(a1, g.y * inv, b.y), 0.f);
      *reinterpret_cast<float2*>(out + (size_t)node * 64 + l5 * 2) = o;
    }
  }
}

// ---------------- Segment mean pool (seg sorted): p[64,64] ----------------

__global__ __launch_bounds__(1024) void pool_kernel(const float* __restrict__ h,
                                                    const int* __restrict__ seg,
                                                    float* __restrict__ p, int n) {
  int g = blockIdx.x;
  int lo, hi;
  { int l = 0, r = n; while (l < r) { int m = (l + r) >> 1; if (seg[m] < g) l = m + 1; else r = m; } lo = l; }
  { int l = 0, r = n; while (l < r) { int m = (l + r) >> 1; if (seg[m] < g + 1) l = m + 1; else r = m; } hi = l; }
  int c = threadIdx.x & 63;
  int sub = threadIdx.x >> 6;
  float acc = 0.f;
  for (int i = lo + sub; i < hi; i += 16) acc += h[(size_t)i * 64 + c];
  __shared__ float red[16][64];
  red[sub][c] = acc;
  __syncthreads();
  if (sub == 0) {
    float s = 0.f;
    #pragma unroll
    for (int k = 0; k < 16; ++k) s += red[k][c];
    float cnt = (float)(hi - lo);
    p[g * 64 + c] = s / fmaxf(cnt, 1.0f);
  }
}

// ---------------- Head: concat -> 2x Dense(128,relu, shared W) -> sigmoid ----------------

__global__ __launch_bounds__(512) void head_kernel(const float* __restrict__ p,
                                                   const float* __restrict__ Wd,
                                                   const float* __restrict__ bd,
                                                   const float* __restrict__ Wo,
                                                   const float* __restrict__ bo,
                                                   float* __restrict__ out) {
  __shared__ float cur[64][128];
  __shared__ float nxt[64][128];
  int tid = threadIdx.x;
  const float* p1 = p;
  const float* p2 = p + 64 * 64;
  for (int i = tid; i < 64 * 128; i += 512) {
    int r = i >> 7, c = i & 127;
    cur[r][c] = (c < 64) ? p1[r * 64 + c] : p2[r * 64 + (c - 64)];
  }
  __syncthreads();
  int c0 = (tid & 31) * 4;
  int r0 = (tid >> 5) * 4;
  for (int layer = 0; layer < 2; ++layer) {
    float acc[4][4] = {};
    #pragma unroll 4
    for (int k = 0; k < 128; ++k) {
      float4 w = *reinterpret_cast<const float4*>(&Wd[k * 128 + c0]);
      #pragma unroll
      for (int i = 0; i < 4; ++i) {
        float x = cur[r0 + i][k];
        acc[i][0] = fmaf(x, w.x, acc[i][0]);
        acc[i][1] = fmaf(x, w.y, acc[i][1]);
        acc[i][2] = fmaf(x, w.z, acc[i][2]);
        acc[i][3] = fmaf(x, w.w, acc[i][3]);
      }
    }
    float4 bv = *reinterpret_cast<const float4*>(&bd[c0]);
    __syncthreads();
    #pragma unroll
    for (int i = 0; i < 4; ++i) {
      float4 o;
      o.x = fmaxf(acc[i][0] + bv.x, 0.f);
      o.y = fmaxf(acc[i][1] + bv.y, 0.f);
      o.z = fmaxf(acc[i][2] + bv.z, 0.f);
      o.w = fmaxf(acc[i][3] + bv.w, 0.f);
      *reinterpret_cast<float4*>(&nxt[r0 + i][c0]) = o;
    }
    __syncthreads();
    for (int i = tid; i < 64 * 128; i += 512) (&cur[0][0])[i] = (&nxt[0][0])[i];
    __syncthreads();
  }
  int wv = tid >> 6, lane = tid & 63;
  for (int r = wv; r < 64; r += 8) {
    float v = cur[r][lane] * Wo[lane] + cur[r][64 + lane] * Wo[64 + lane];
    #pragma unroll
    for (int off = 32; off; off >>= 1) v += __shfl_down(v, off);
    if (lane == 0) out[r] = 1.0f / (1.0f + expf(-(v + bo[0])));
  }
}

// ---------------- launch ----------------

extern "C" void kernel_launch(void* const* d_in, const int* in_sizes, int n_in,
                              void* d_out, int out_size, void* d_ws, size_t ws_size,
                              hipStream_t stream) {
  const float* x1  = (const float*)d_in[0];
  const float* x2  = (const float*)d_in[1];
  const int* e1    = (const int*)d_in[2];
  const int* e2    = (const int*)d_in[3];
  const int* seg1  = (const int*)d_in[4];
  const int* seg2  = (const int*)d_in[5];
  const float* W1a = (const float*)d_in[6];  const float* b1a = (const float*)d_in[7];
  const float* g1a = (const float*)d_in[8];  const float* be1a = (const float*)d_in[9];
  const float* W1b = (const float*)d_in[10]; const float* b1b = (const float*)d_in[11];
  const float* g1b = (const float*)d_in[12]; const float* be1b = (const float*)d_in[13];
  const float* W2a = (const float*)d_in[14]; const float* b2a = (const float*)d_in[15];
  const float* g2a = (const float*)d_in[16]; const float* be2a = (const float*)d_in[17];
  const float* W2b = (const float*)d_in[18]; const float* b2b = (const float*)d_in[19];
  const float* g2b = (const float*)d_in[20]; const float* be2b = (const float*)d_in[21];
  const float* Wd  = (const float*)d_in[22]; const float* bd  = (const float*)d_in[23];
  const float* Wo  = (const float*)d_in[24]; const float* bo  = (const float*)d_in[25];
  float* out = (float*)d_out;

  const int N = in_sizes[0] / 128;
  const int E = in_sizes[2] / 2;
  const int G1 = (N + GS - 1) >> GSH;   // 98 for N=50000
  const int G  = 2 * G1;

  char* ws = (char*)d_ws;
  size_t off = 0;
  auto alloc = [&](size_t bytes) -> void* {
    void* ptr = ws + off;
    off += (bytes + 255) & ~(size_t)255;
    return ptr;
  };
  float* h    = (float*)alloc((size_t)N * 128 * sizeof(float));
  float* aggb = (float*)alloc((size_t)N * 128 * sizeof(float));
  int* pairs  = (int*)alloc((size_t)G * SCAP * sizeof(int));  // becomes csr in-place
  int* offs   = (int*)alloc((size_t)(2 * N) * sizeof(int));
  int* counts = (int*)alloc((size_t)(2 * N) * sizeof(int));
  int* gcur   = (int*)alloc((size_t)(G + 8) * sizeof(int));
  float* pbuf = (float*)alloc(2 * 64 * 64 * sizeof(float));
  (void)ws_size; (void)n_in; (void)out_size;

  // ---- CSR build: coarse bin (dense chunked writes) + per-group refine (in-place) ----
  hipMemsetAsync(gcur, 0, (size_t)(G + 8) * sizeof(int), stream);
  {
    dim3 gb((E + 4095) / 4096, 2);
    bin_kernel<<<gb, 1024, 0, stream>>>(e1, e1 + E, e2, e2 + E, gcur, pairs, E, G1);
    dim3 gr(G1, 2);
    refine_kernel<<<gr, 1024, 0, stream>>>(gcur, pairs, offs, counts, N, G1);
  }

  struct Branch {
    const float *x; const int *seg;
    const float *Wa, *ba, *ga, *bea, *Wb, *bb, *gb, *beb;
  };
  Branch brs[2] = {
    {x1, seg1, W1a, b1a, g1a, be1a, W1b, b1b, g1b, be1b},
    {x2, seg2, W2a, b2a, g2a, be2a, W2b, b2b, g2b, be2b},
  };

  for (int b = 0; b < 2; ++b) {
    const int* offs_b = offs + b * N;
    const int* cnts_b = counts + b * N;
    gemm_kernel<128><<<(N + 63) / 64, 256, 0, stream>>>(brs[b].x, brs[b].Wa, brs[b].ba, h, N);
    agg_kernel<128><<<(N + 3) / 4, 256, 0, stream>>>(h, offs_b, cnts_b, pairs, brs[b].ga, brs[b].bea, aggb, N);
    gemm_kernel<64><<<(N + 63) / 64, 256, 0, stream>>>(aggb, brs[b].Wb, brs[b].bb, h, N);
    agg_kernel<64><<<(N + 3) / 4, 256, 0, stream>>>(h, offs_b, cnts_b, pairs, brs[b].gb, brs[b].beb, aggb, N);
    pool_kernel<<<64, 1024, 0, stream>>>(aggb, brs[b].seg, pbuf + b * 64 * 64, N);
  }
  head_kernel<<<1, 512, 0, stream>>>(pbuf, Wd, bd, Wo, bo, out);
}

// Round 10
// 336.637 us; speedup vs baseline: 7.2602x; 1.1292x over previous
//
#include <hip/hip_runtime.h>
#include <math.h>

#define GS    512   // nodes per group
#define GSH   9
#define NGMAX 128   // max groups per branch (G1=98 for N=50000)
#define FCAP  48    // LDS FIFO capacity per group per round
#define SCAP  10240 // group region capacity

// ---------------- pass 1: bin edges into 512-node groups ----------------

__global__ __launch_bounds__(1024) void bin_kernel(
    const int* __restrict__ s1, const int* __restrict__ d1,
    const int* __restrict__ s2, const int* __restrict__ d2,
    int* __restrict__ gcur, int* __restrict__ pairs, int E, int G1) {
  __shared__ int fifo[NGMAX][FCAP];
  __shared__ int fcnt[NGMAX];
  __shared__ int fbase[NGMAX];
  __shared__ int fpre[NGMAX + 1];
  const int* src = blockIdx.y ? s2 : s1;
  const int* dst = blockIdx.y ? d2 : d1;
  int gboff = blockIdx.y * G1;
  int tid = threadIdx.x;
  if (tid < NGMAX) fcnt[tid] = 0;
  __syncthreads();
  int e0 = blockIdx.x * 4096;
  for (int r = 0; r < 4; ++r) {
    int e = e0 + r * 1024 + tid;
    if (e < E) {
      int s = src[e], d = dst[e];
      int g = d >> GSH;
      int pk = s | ((d & (GS - 1)) << 17);
      int pos = atomicAdd(&fcnt[g], 1);
      if (pos < FCAP) fifo[g][pos] = pk;
      else {
        int gp = atomicAdd(&gcur[gboff + g], 1);
        pairs[(size_t)(gboff + g) * SCAP + gp] = pk;
      }
    }
    __syncthreads();
    if (tid < G1) {
      int c = fcnt[tid];
      if (c > FCAP) c = FCAP;
      fcnt[tid] = c;
      fbase[tid] = (c > 0) ? atomicAdd(&gcur[gboff + tid], c) : 0;
    }
    __syncthreads();
    if (tid == 0) {
      int acc = 0;
      for (int i = 0; i < G1; ++i) { fpre[i] = acc; acc += fcnt[i]; }
      fpre[G1] = acc;
    }
    __syncthreads();
    int T = fpre[G1];
    for (int t = tid; t < T; t += 1024) {
      int lo = 0, hi = G1;
      while (hi - lo > 1) { int mid = (lo + hi) >> 1; if (fpre[mid] <= t) lo = mid; else hi = mid; }
      int idx = t - fpre[lo];
      pairs[(size_t)(gboff + lo) * SCAP + fbase[lo] + idx] = fifo[lo][idx];
    }
    __syncthreads();
    if (tid < NGMAX) fcnt[tid] = 0;
    __syncthreads();
  }
}

// ---------------- pass 2: per-group node CSR, in-place ----------------

__global__ __launch_bounds__(1024) void refine_kernel(
    const int* __restrict__ gcur, int* __restrict__ pairs,
    int* __restrict__ offs, int* __restrict__ counts, int N, int G1) {
  __shared__ int stg[SCAP];
  __shared__ int hist[GS];
  __shared__ int excl[GS];
  __shared__ int wtot[8];
  int gl = blockIdx.x, br = blockIdx.y;
  int g = br * G1 + gl;
  size_t rbase = (size_t)g * SCAP;
  int rcnt = gcur[g];
  if (rcnt > SCAP) rcnt = SCAP;
  int tid = threadIdx.x;
  if (tid < GS) hist[tid] = 0;
  __syncthreads();
  for (int i = tid; i < rcnt; i += 1024) {
    int pk = pairs[rbase + i];
    stg[i] = pk;
    atomicAdd(&hist[pk >> 17], 1);
  }
  __syncthreads();
  if (tid < GS) {
    int lane = tid & 63, wv = tid >> 6;
    int v = hist[tid];
    int inc = v;
    #pragma unroll
    for (int off = 1; off < 64; off <<= 1) {
      int t = __shfl_up(inc, off);
      if (lane >= off) inc += t;
    }
    excl[tid] = inc - v;
    if (lane == 63) wtot[wv] = inc;
  }
  __syncthreads();
  if (tid == 0) {
    int a = 0;
    #pragma unroll
    for (int w = 0; w < 8; ++w) { int t = wtot[w]; wtot[w] = a; a += t; }
  }
  __syncthreads();
  if (tid < GS) excl[tid] += wtot[tid >> 6];
  __syncthreads();
  int node0 = gl * GS;
  int nloc = N - node0; if (nloc > GS) nloc = GS;
  for (int j = tid; j < nloc; j += 1024) {
    offs[br * N + node0 + j] = (int)rbase + excl[j];
    counts[br * N + node0 + j] = hist[j];
  }
  __syncthreads();
  for (int i = tid; i < rcnt; i += 1024) {
    int pk = stg[i];
    int pos = atomicAdd(&excl[pk >> 17], 1);
    pairs[rbase + pos] = pk & 0x1FFFF;
  }
}

// ---------------- GEMM both branches: Y[br][nrows,COUT] = X[br] @ W[br] + b[br] ----------------

template <int COUT>
__global__ __launch_bounds__(256, 2) void gemm2_kernel(
    const float* __restrict__ X0, const float* __restrict__ X1,
    const float* __restrict__ W0, const float* __restrict__ W1,
    const float* __restrict__ bias0, const float* __restrict__ bias1,
    float* __restrict__ Y0, float* __restrict__ Y1, int nrows) {
  constexpr int CG = COUT / 4;
  constexpr int RG = 256 / CG;
  constexpr int BM = 64;
  constexpr int RPT = BM / RG;
  const float* X = blockIdx.y ? X1 : X0;
  const float* W = blockIdx.y ? W1 : W0;
  const float* bias = blockIdx.y ? bias1 : bias0;
  float* Y = blockIdx.y ? Y1 : Y0;
  __shared__ float xs[BM][132];
  int tid = threadIdx.x;
  int block_row = blockIdx.x * BM;
  for (int i = tid; i < BM * 32; i += 256) {
    int r = i >> 5, c4 = i & 31;
    int gr = block_row + r;
    float4 v = make_float4(0.f, 0.f, 0.f, 0.f);
    if (gr < nrows) v = reinterpret_cast<const float4*>(X + (size_t)gr * 128)[c4];
    *reinterpret_cast<float4*>(&xs[r][c4 * 4]) = v;
  }
  __syncthreads();
  int c0 = (tid % CG) * 4;
  int r0 = (tid / CG) * RPT;
  float acc[RPT][4] = {};
  #pragma unroll 2
  for (int k = 0; k < 128; k += 4) {
    float4 w0 = *reinterpret_cast<const float4*>(&W[(k + 0) * COUT + c0]);
    float4 w1 = *reinterpret_cast<const float4*>(&W[(k + 1) * COUT + c0]);
    float4 w2 = *reinterpret_cast<const float4*>(&W[(k + 2) * COUT + c0]);
    float4 w3 = *reinterpret_cast<const float4*>(&W[(k + 3) * COUT + c0]);
    #pragma unroll
    for (int i = 0; i < RPT; ++i) {
      float4 x = *reinterpret_cast<const float4*>(&xs[r0 + i][k]);
      acc[i][0] = fmaf(x.x, w0.x, acc[i][0]);
      acc[i][1] = fmaf(x.x, w0.y, acc[i][1]);
      acc[i][2] = fmaf(x.x, w0.z, acc[i][2]);
      acc[i][3] = fmaf(x.x, w0.w, acc[i][3]);
      acc[i][0] = fmaf(x.y, w1.x, acc[i][0]);
      acc[i][1] = fmaf(x.y, w1.y, acc[i][1]);
      acc[i][2] = fmaf(x.y, w1.z, acc[i][2]);
      acc[i][3] = fmaf(x.y, w1.w, acc[i][3]);
      acc[i][0] = fmaf(x.z, w2.x, acc[i][0]);
      acc[i][1] = fmaf(x.z, w2.y, acc[i][1]);
      acc[i][2] = fmaf(x.z, w2.z, acc[i][2]);
      acc[i][3] = fmaf(x.z, w2.w, acc[i][3]);
      acc[i][0] = fmaf(x.w, w3.x, acc[i][0]);
      acc[i][1] = fmaf(x.w, w3.y, acc[i][1]);
      acc[i][2] = fmaf(x.w, w3.z, acc[i][2]);
      acc[i][3] = fmaf(x.w, w3.w, acc[i][3]);
    }
  }
  float4 bv = *reinterpret_cast<const float4*>(&bias[c0]);
  #pragma unroll
  for (int i = 0; i < RPT; ++i) {
    int gr = block_row + r0 + i;
    if (gr < nrows) {
      float4 o;
      o.x = acc[i][0] + bv.x; o.y = acc[i][1] + bv.y;
      o.z = acc[i][2] + bv.z; o.w = acc[i][3] + bv.w;
      *reinterpret_cast<float4*>(&Y[(size_t)gr * COUT + c0]) = o;
    }
  }
}

// ---------------- agg C=128, column-split (blockIdx.y = col half) ----------------
// Each block: 4 nodes x 64 cols; 256B/edge via float2/lane; halves instantaneous
// table working set (blocks dispatch x-fastest) -> better L2 hit rate.

__global__ __launch_bounds__(256) void agg128_kernel(
    const float* __restrict__ h, const int* __restrict__ offs,
    const int* __restrict__ counts, const int* __restrict__ csr_src,
    const float* __restrict__ gamma, const float* __restrict__ beta,
    float* __restrict__ out, int n) {
  int node = blockIdx.x * 4 + (threadIdx.x >> 6);
  if (node >= n) return;
  node = __builtin_amdgcn_readfirstlane(node);
  int ch = blockIdx.y;              // column half
  int lane = threadIdx.x & 63;
  int half = lane >> 5;
  int l5 = lane & 31;
  const float* hh = h + ch * 64;
  int beg = offs[node], cnt = counts[node];
  const int* lp = csr_src + beg;
  float a0 = 0.f, a1 = 0.f;
  for (int base = 0; base < cnt; base += 64) {
    int rem = cnt - base;
    int m = rem < 64 ? rem : 64;
    int idx = lp[base + (lane < m ? lane : m - 1)];
    int mfull = m & ~15;
    int j = 0;
    for (; j < mfull; j += 16) {
      float2 v[8];
      #pragma unroll
      for (int u = 0; u < 8; ++u) {
        int s = __shfl(idx, j + 2 * u + half);
        v[u] = *reinterpret_cast<const float2*>(hh + (size_t)s * 128 + l5 * 2);
      }
      #pragma unroll
      for (int u = 0; u < 8; ++u) { a0 += v[u].x; a1 += v[u].y; }
    }
    if (j < m) {
      float2 v[8];
      #pragma unroll
      for (int u = 0; u < 8; ++u) {
        int ed = j + 2 * u + half;
        int s = __shfl(idx, ed < m ? ed : m - 1);
        v[u] = *reinterpret_cast<const float2*>(hh + (size_t)s * 128 + l5 * 2);
      }
      #pragma unroll
      for (int u = 0; u < 8; ++u) {
        bool ok = (j + 2 * u + half) < m;
        a0 += ok ? v[u].x : 0.f;
        a1 += ok ? v[u].y : 0.f;
      }
    }
  }
  a0 += __shfl_xor(a0, 32);
  a1 += __shfl_xor(a1, 32);
  const float inv = 1.0f / sqrtf(1.0f + 1.0e-3f);
  if (half == 0) {
    float2 g = reinterpret_cast<const float2*>(gamma + ch * 64)[l5];
    float2 b = reinterpret_cast<const float2*>(beta + ch * 64)[l5];
    float2 o;
    o.x = fmaxf(fmaf(a0, g.x * inv, b.x), 0.f);
    o.y = fmaxf(fmaf(a1, g.y * inv, b.y), 0.f);
    *reinterpret_cast<float2*>(out + (size_t)node * 128 + ch * 64 + l5 * 2) = o;
  }
}

// ---------------- agg C=64 (unsplit; table 12.8 MB) ----------------

__global__ __launch_bounds__(256) void agg64_kernel(
    const float* __restrict__ h, const int* __restrict__ offs,
    const int* __restrict__ counts, const int* __restrict__ csr_src,
    const float* __restrict__ gamma, const float* __restrict__ beta,
    float* __restrict__ out, int n) {
  int node = blockIdx.x * 4 + (threadIdx.x >> 6);
  if (node >= n) return;
  node = __builtin_amdgcn_readfirstlane(node);
  int lane = threadIdx.x & 63;
  int half = lane >> 5;
  int l5 = lane & 31;
  int beg = offs[node], cnt = counts[node];
  const int* lp = csr_src + beg;
  float a0 = 0.f, a1 = 0.f;
  for (int base = 0; base < cnt; base += 64) {
    int rem = cnt - base;
    int m = rem < 64 ? rem : 64;
    int idx = lp[base + (lane < m ? lane : m - 1)];
    int mfull = m & ~15;
    int j = 0;
    for (; j < mfull; j += 16) {
      float2 v[8];
      #pragma unroll
      for (int u = 0; u < 8; ++u) {
        int s = __shfl(idx, j + 2 * u + half);
        v[u] = *reinterpret_cast<const float2*>(h + (size_t)s * 64 + l5 * 2);
      }
      #pragma unroll
      for (int u = 0; u < 8; ++u) { a0 += v[u].x; a1 += v[u].y; }
    }
    if (j < m) {
      float2 v[8];
      #pragma unroll
      for (int u = 0; u < 8; ++u) {
        int ed = j + 2 * u + half;
        int s = __shfl(idx, ed < m ? ed : m - 1);
        v[u] = *reinterpret_cast<const float2*>(h + (size_t)s * 64 + l5 * 2);
      }
      #pragma unroll
      for (int u = 0; u < 8; ++u) {
        bool ok = (j + 2 * u + half) < m;
        a0 += ok ? v[u].x : 0.f;
        a1 += ok ? v[u].y : 0.f;
      }
    }
  }
  a0 += __shfl_xor(a0, 32);
  a1 += __shfl_xor(a1, 32);
  const float inv = 1.0f / sqrtf(1.0f + 1.0e-3f);
  if (half == 0) {
    float2 g = reinterpret_cast<const float2*>(gamma)[l5];
    float2 b = reinterpret_cast<const float2*>(beta)[l5];
    float2 o;
    o.x = fmaxf(fmaf(a0, g.x * inv, b.x), 0.f);
    o.y = fmaxf(fmaf(a1, g.y * inv, b.y), 0.f);
    *reinterpret_cast<float2*>(out + (size_t)node * 64 + l5 * 2) = o;
  }
}

// ---------------- Segment mean pool, both branches (blockIdx.y = branch) ----------------

__global__ __launch_bounds__(1024) void pool2_kernel(
    const float* __restrict__ h0, const float* __restrict__ h1,
    const int* __restrict__ seg0, const int* __restrict__ seg1,
    float* __restrict__ p, int n) {
  const float* h = blockIdx.y ? h1 : h0;
  const int* seg = blockIdx.y ? seg1 : seg0;
  float* pb = p + blockIdx.y * 64 * 64;
  int g = blockIdx.x;
  int lo, hi;
  { int l = 0, r = n; while (l < r) { int m = (l + r) >> 1; if (seg[m] < g) l = m + 1; else r = m; } lo = l; }
  { int l = 0, r = n; while (l < r) { int m = (l + r) >> 1; if (seg[m] < g + 1) l = m + 1; else r = m; } hi = l; }
  int c = threadIdx.x & 63;
  int sub = threadIdx.x >> 6;
  float acc = 0.f;
  for (int i = lo + sub; i < hi; i += 16) acc += h[(size_t)i * 64 + c];
  __shared__ float red[16][64];
  red[sub][c] = acc;
  __syncthreads();
  if (sub == 0) {
    float s = 0.f;
    #pragma unroll
    for (int k = 0; k < 16; ++k) s += red[k][c];
    float cnt = (float)(hi - lo);
    pb[g * 64 + c] = s / fmaxf(cnt, 1.0f);
  }
}

// ---------------- Head ----------------

__global__ __launch_bounds__(512) void head_kernel(const float* __restrict__ p,
                                                   const float* __restrict__ Wd,
                                                   const float* __restrict__ bd,
                                                   const float* __restrict__ Wo,
                                                   const float* __restrict__ bo,
                                                   float* __restrict__ out) {
  __shared__ float cur[64][128];
  __shared__ float nxt[64][128];
  int tid = threadIdx.x;
  const float* p1 = p;
  const float* p2 = p + 64 * 64;
  for (int i = tid; i < 64 * 128; i += 512) {
    int r = i >> 7, c = i & 127;
    cur[r][c] = (c < 64) ? p1[r * 64 + c] : p2[r * 64 + (c - 64)];
  }
  __syncthreads();
  int c0 = (tid & 31) * 4;
  int r0 = (tid >> 5) * 4;
  for (int layer = 0; layer < 2; ++layer) {
    float acc[4][4] = {};
    #pragma unroll 4
    for (int k = 0; k < 128; ++k) {
      float4 w = *reinterpret_cast<const float4*>(&Wd[k * 128 + c0]);
      #pragma unroll
      for (int i = 0; i < 4; ++i) {
        float x = cur[r0 + i][k];
        acc[i][0] = fmaf(x, w.x, acc[i][0]);
        acc[i][1] = fmaf(x, w.y, acc[i][1]);
        acc[i][2] = fmaf(x, w.z, acc[i][2]);
        acc[i][3] = fmaf(x, w.w, acc[i][3]);
      }
    }
    float4 bv = *reinterpret_cast<const float4*>(&bd[c0]);
    __syncthreads();
    #pragma unroll
    for (int i = 0; i < 4; ++i) {
      float4 o;
      o.x = fmaxf(acc[i][0] + bv.x, 0.f);
      o.y = fmaxf(acc[i][1] + bv.y, 0.f);
      o.z = fmaxf(acc[i][2] + bv.z, 0.f);
      o.w = fmaxf(acc[i][3] + bv.w, 0.f);
      *reinterpret_cast<float4*>(&nxt[r0 + i][c0]) = o;
    }
    __syncthreads();
    for (int i = tid; i < 64 * 128; i += 512) (&cur[0][0])[i] = (&nxt[0][0])[i];
    __syncthreads();
  }
  int wv = tid >> 6, lane = tid & 63;
  for (int r = wv; r < 64; r += 8) {
    float v = cur[r][lane] * Wo[lane] + cur[r][64 + lane] * Wo[64 + lane];
    #pragma unroll
    for (int off = 32; off; off >>= 1) v += __shfl_down(v, off);
    if (lane == 0) out[r] = 1.0f / (1.0f + expf(-(v + bo[0])));
  }
}

// ---------------- launch ----------------

extern "C" void kernel_launch(void* const* d_in, const int* in_sizes, int n_in,
                              void* d_out, int out_size, void* d_ws, size_t ws_size,
                              hipStream_t stream) {
  const float* x1  = (const float*)d_in[0];
  const float* x2  = (const float*)d_in[1];
  const int* e1    = (const int*)d_in[2];
  const int* e2    = (const int*)d_in[3];
  const int* seg1  = (const int*)d_in[4];
  const int* seg2  = (const int*)d_in[5];
  const float* W1a = (const float*)d_in[6];  const float* b1a = (const float*)d_in[7];
  const float* g1a = (const float*)d_in[8];  const float* be1a = (const float*)d_in[9];
  const float* W1b = (const float*)d_in[10]; const float* b1b = (const float*)d_in[11];
  const float* g1b = (const float*)d_in[12]; const float* be1b = (const float*)d_in[13];
  const float* W2a = (const float*)d_in[14]; const float* b2a = (const float*)d_in[15];
  const float* g2a = (const float*)d_in[16]; const float* be2a = (const float*)d_in[17];
  const float* W2b = (const float*)d_in[18]; const float* b2b = (const float*)d_in[19];
  const float* g2b = (const float*)d_in[20]; const float* be2b = (const float*)d_in[21];
  const float* Wd  = (const float*)d_in[22]; const float* bd  = (const float*)d_in[23];
  const float* Wo  = (const float*)d_in[24]; const float* bo  = (const float*)d_in[25];
  float* out = (float*)d_out;

  const int N = in_sizes[0] / 128;
  const int E = in_sizes[2] / 2;
  const int G1 = (N + GS - 1) >> GSH;
  const int G  = 2 * G1;

  char* ws = (char*)d_ws;
  size_t off = 0;
  auto alloc = [&](size_t bytes) -> void* {
    void* ptr = ws + off;
    off += (bytes + 255) & ~(size_t)255;
    return ptr;
  };
  float* h0   = (float*)alloc((size_t)N * 128 * sizeof(float));
  float* h1   = (float*)alloc((size_t)N * 128 * sizeof(float));
  float* ag0  = (float*)alloc((size_t)N * 128 * sizeof(float));
  float* ag1  = (float*)alloc((size_t)N * 128 * sizeof(float));
  int* pairs  = (int*)alloc((size_t)G * SCAP * sizeof(int));
  int* offs   = (int*)alloc((size_t)(2 * N) * sizeof(int));
  int* counts = (int*)alloc((size_t)(2 * N) * sizeof(int));
  int* gcur   = (int*)alloc((size_t)(G + 8) * sizeof(int));
  float* pbuf = (float*)alloc(2 * 64 * 64 * sizeof(float));
  (void)ws_size; (void)n_in; (void)out_size;

  // ---- CSR build ----
  hipMemsetAsync(gcur, 0, (size_t)(G + 8) * sizeof(int), stream);
  {
    dim3 gb((E + 4095) / 4096, 2);
    bin_kernel<<<gb, 1024, 0, stream>>>(e1, e1 + E, e2, e2 + E, gcur, pairs, E, G1);
    dim3 gr(G1, 2);
    refine_kernel<<<gr, 1024, 0, stream>>>(gcur, pairs, offs, counts, N, G1);
  }

  const int* offs0 = offs;       const int* cnts0 = counts;
  const int* offs1 = offs + N;   const int* cnts1 = counts + N;

  // layer 1: GEMM both branches, then per-branch col-split agg
  {
    dim3 gg((N + 63) / 64, 2);
    gemm2_kernel<128><<<gg, 256, 0, stream>>>(x1, x2, W1a, W2a, b1a, b2a, h0, h1, N);
  }
  {
    dim3 ga((N + 3) / 4, 2);
    agg128_kernel<<<ga, 256, 0, stream>>>(h0, offs0, cnts0, pairs, g1a, be1a, ag0, N);
    agg128_kernel<<<ga, 256, 0, stream>>>(h1, offs1, cnts1, pairs, g2a, be2a, ag1, N);
  }
  // layer 2
  {
    dim3 gg((N + 63) / 64, 2);
    gemm2_kernel<64><<<gg, 256, 0, stream>>>(ag0, ag1, W1b, W2b, b1b, b2b, h0, h1, N);
  }
  agg64_kernel<<<(N + 3) / 4, 256, 0, stream>>>(h0, offs0, cnts0, pairs, g1b, be1b, ag0, N);
  agg64_kernel<<<(N + 3) / 4, 256, 0, stream>>>(h1, offs1, cnts1, pairs, g2b, be2b, ag1, N);
  // pool both branches + head
  {
    dim3 gp(64, 2);
    pool2_kernel<<<gp, 1024, 0, stream>>>(ag0, ag1, seg1, seg2, pbuf, N);
  }
  head_kernel<<<1, 512, 0, stream>>>(pbuf, Wd, bd, Wo, bo, out);
}